// Round 1
// baseline (744.108 us; speedup 1.0000x reference)
//
#include <hip/hip_runtime.h>

typedef _Float16 f16;
typedef f16 f16x8 __attribute__((ext_vector_type(8)));
typedef float f32x4 __attribute__((ext_vector_type(4)));

#define IN_CH  256
#define HID    256
#define OUT_CH 128
#define LN_EPS 1e-5f

// ---------------- graph preprocessing ----------------

__global__ void k_hist(const int* __restrict__ ei, int nE, int nN,
                       int* __restrict__ deg, int* __restrict__ counts) {
    int e = blockIdx.x * blockDim.x + threadIdx.x;
    int total = nE + nN;
    if (e >= total) return;
    int s, d;
    if (e < nE) { s = ei[e]; d = ei[nE + e]; } else { s = d = e - nE; }
    atomicAdd(&deg[s], 1);
    atomicAdd(&counts[d], 1);
}

__global__ __launch_bounds__(1024) void k_scan(const int* __restrict__ counts, int nN,
                                               int* __restrict__ row_ptr) {
    __shared__ int sums[1024];
    int tid = threadIdx.x;
    int per = (nN + 1023) / 1024;
    int start = tid * per;
    int end = start + per; if (end > nN) end = nN;
    int local = 0;
    for (int i = start; i < end; i++) local += counts[i];
    sums[tid] = local;
    __syncthreads();
    for (int off = 1; off < 1024; off <<= 1) {
        int v = (tid >= off) ? sums[tid - off] : 0;
        __syncthreads();
        sums[tid] += v;
        __syncthreads();
    }
    int run = sums[tid] - local;  // exclusive prefix
    for (int i = start; i < end; i++) { row_ptr[i] = run; run += counts[i]; }
    if (tid == 1023) row_ptr[nN] = sums[1023];
}

__global__ void k_dinv(const int* __restrict__ deg, float* __restrict__ dinv, int nN) {
    int i = blockIdx.x * blockDim.x + threadIdx.x;
    if (i < nN) dinv[i] = rsqrtf((float)deg[i]);  // deg >= 1 (self loop)
}

__global__ void k_fill(const int* __restrict__ ei, int nE, int nN,
                       const float* __restrict__ dinv, const int* __restrict__ row_ptr,
                       int* __restrict__ fillc, int* __restrict__ src_sorted,
                       float* __restrict__ norm_sorted) {
    int e = blockIdx.x * blockDim.x + threadIdx.x;
    int total = nE + nN;
    if (e >= total) return;
    int s, d;
    if (e < nE) { s = ei[e]; d = ei[nE + e]; } else { s = d = e - nE; }
    float nm = dinv[s] * dinv[d];
    int pos = row_ptr[d] + atomicAdd(&fillc[d], 1);
    src_sorted[pos] = s;
    norm_sorted[pos] = nm;
}

// ---------------- weight prep: fp32 -> fp16, transposed to [N][K] ----------------

__global__ void k_prepw(const float* __restrict__ sigw, const float* __restrict__ c1w,
                        const float* __restrict__ c2w,
                        f16* __restrict__ Wt1, f16* __restrict__ Wt2) {
    int i = blockIdx.x * 256 + threadIdx.x;
    if (i < 512 * 256) {
        int n = i >> 8, k = i & 255;
        float v = (n < 256) ? sigw[k * 256 + n] : c1w[k * 256 + (n - 256)];
        Wt1[(size_t)n * 256 + k] = (f16)v;
    } else {
        int j = i - 512 * 256;
        if (j < 128 * 256) {
            int n = j >> 8, k = j & 255;
            Wt2[(size_t)n * 256 + k] = (f16)c2w[k * 128 + n];
        }
    }
}

// ---------------- GEMM1: Y[M,512] = x[M,256] @ [sig_w | conv1_w]  (fp16 MFMA) ----------------
// block = 4 waves; wave covers 32 rows x 64 cols; block = 32 rows x 256 cols; grid=(2, ceil(M/32))

__global__ __launch_bounds__(256) void k_gemm1(const float* __restrict__ X,
                                               const f16* __restrict__ Wt, f16* __restrict__ Y,
                                               int M) {
    int t = threadIdx.x;
    int w = t >> 6, lane = t & 63, quad = lane >> 4, l16 = lane & 15;
    int m0 = blockIdx.y * 32;
    int cb = blockIdx.x * 256 + w * 64;
    f32x4 acc[2][4] = {};
    for (int kk = 0; kk < 256; kk += 32) {
        int ka = kk + quad * 8;
        f16x8 a[2];
        for (int ms = 0; ms < 2; ms++) {
            int row = m0 + ms * 16 + l16; if (row >= M) row = M - 1;
            const float* p = X + (size_t)row * 256 + ka;
            float4 x0 = *(const float4*)p;
            float4 x1 = *(const float4*)(p + 4);
            f16x8 af = { (f16)x0.x, (f16)x0.y, (f16)x0.z, (f16)x0.w,
                         (f16)x1.x, (f16)x1.y, (f16)x1.z, (f16)x1.w };
            a[ms] = af;
        }
        for (int ns = 0; ns < 4; ns++) {
            f16x8 b = *(const f16x8*)(Wt + (size_t)(cb + ns * 16 + l16) * 256 + ka);
            acc[0][ns] = __builtin_amdgcn_mfma_f32_16x16x32_f16(a[0], b, acc[0][ns], 0, 0, 0);
            acc[1][ns] = __builtin_amdgcn_mfma_f32_16x16x32_f16(a[1], b, acc[1][ns], 0, 0, 0);
        }
    }
    for (int ms = 0; ms < 2; ms++)
        for (int ns = 0; ns < 4; ns++)
            for (int r = 0; r < 4; r++) {
                int m = m0 + ms * 16 + quad * 4 + r;  // D: row=(lane>>4)*4+reg, col=lane&15
                if (m < M) Y[(size_t)m * 512 + cb + ns * 16 + l16] = (f16)acc[ms][ns][r];
            }
}

// ---------------- GEMM2: HW[M,128] = H[M,256](fp16) @ conv2_w ----------------
// wave covers 32 rows x 32 cols; block 4 waves = 32 rows x 128 cols; grid=(1, ceil(M/32))

__global__ __launch_bounds__(256) void k_gemm2(const f16* __restrict__ H,
                                               const f16* __restrict__ Wt, f16* __restrict__ HW,
                                               int M) {
    int t = threadIdx.x;
    int w = t >> 6, lane = t & 63, quad = lane >> 4, l16 = lane & 15;
    int m0 = blockIdx.y * 32;
    int cb = w * 32;
    f32x4 acc[2][2] = {};
    for (int kk = 0; kk < 256; kk += 32) {
        int ka = kk + quad * 8;
        f16x8 a[2];
        for (int ms = 0; ms < 2; ms++) {
            int row = m0 + ms * 16 + l16; if (row >= M) row = M - 1;
            a[ms] = *(const f16x8*)(H + (size_t)row * 256 + ka);
        }
        for (int ns = 0; ns < 2; ns++) {
            f16x8 b = *(const f16x8*)(Wt + (size_t)(cb + ns * 16 + l16) * 256 + ka);
            acc[0][ns] = __builtin_amdgcn_mfma_f32_16x16x32_f16(a[0], b, acc[0][ns], 0, 0, 0);
            acc[1][ns] = __builtin_amdgcn_mfma_f32_16x16x32_f16(a[1], b, acc[1][ns], 0, 0, 0);
        }
    }
    for (int ms = 0; ms < 2; ms++)
        for (int ns = 0; ns < 2; ns++)
            for (int r = 0; r < 4; r++) {
                int m = m0 + ms * 16 + quad * 4 + r;
                if (m < M) HW[(size_t)m * 128 + cb + ns * 16 + l16] = (f16)acc[ms][ns][r];
            }
}

// ---------------- aggregation: signature (sum of relu over all nodes) ----------------
// 256 threads = channels, 64 nodes per block, atomicAdd partials into s[256]

__global__ __launch_bounds__(256) void k_aggsig(const f16* __restrict__ Y,
                                                const int* __restrict__ row_ptr,
                                                const int* __restrict__ srcs,
                                                const float* __restrict__ norms,
                                                const float* __restrict__ sigb,
                                                float* __restrict__ s_out, int nN) {
    int ch = threadIdx.x;
    int n0 = blockIdx.x * 64;
    int nend = n0 + 64; if (nend > nN) nend = nN;
    float bias = sigb[ch];
    float loc = 0.f;
    const f16* Yc = Y + ch;  // sig cols 0..255, row stride 512
    for (int n = n0; n < nend; n++) {
        int beg = row_ptr[n], end = row_ptr[n + 1];
        float acc = 0.f;
        int e = beg;
        for (; e + 4 <= end; e += 4) {
            int s0 = srcs[e], s1 = srcs[e + 1], s2 = srcs[e + 2], s3 = srcs[e + 3];
            float nm0 = norms[e], nm1 = norms[e + 1], nm2 = norms[e + 2], nm3 = norms[e + 3];
            float v0 = (float)Yc[(size_t)s0 * 512];
            float v1 = (float)Yc[(size_t)s1 * 512];
            float v2 = (float)Yc[(size_t)s2 * 512];
            float v3 = (float)Yc[(size_t)s3 * 512];
            acc = fmaf(nm0, v0, acc); acc = fmaf(nm1, v1, acc);
            acc = fmaf(nm2, v2, acc); acc = fmaf(nm3, v3, acc);
        }
        for (; e < end; e++)
            acc = fmaf(norms[e], (float)Yc[(size_t)srcs[e] * 512], acc);
        loc += fmaxf(acc + bias, 0.f);
    }
    atomicAdd(&s_out[ch], loc);
}

// ---------------- FC: gamma/beta = tanh(s @ W.T + b), 4 blocks ----------------

__global__ __launch_bounds__(256) void k_fc(const float* __restrict__ s_in,
                                            const float* __restrict__ f1w, const float* __restrict__ f1b,
                                            const float* __restrict__ f2w, const float* __restrict__ f2b,
                                            const float* __restrict__ f3w, const float* __restrict__ f3b,
                                            const float* __restrict__ f4w, const float* __restrict__ f4b,
                                            float* __restrict__ g1, float* __restrict__ b1,
                                            float* __restrict__ g2, float* __restrict__ b2) {
    __shared__ float ss[256];
    int t = threadIdx.x;
    ss[t] = s_in[t];
    __syncthreads();
    const float* w; const float* bias; float* out; int rows;
    switch (blockIdx.x) {
        case 0:  w = f1w; bias = f1b; out = g1; rows = 256; break;
        case 1:  w = f2w; bias = f2b; out = b1; rows = 256; break;
        case 2:  w = f3w; bias = f3b; out = g2; rows = 128; break;
        default: w = f4w; bias = f4b; out = b2; rows = 128; break;
    }
    if (t < rows) {
        float a = 0.f;
        const float* wr = w + (size_t)t * 256;
        for (int j = 0; j < 256; j++) a = fmaf(wr[j], ss[j], a);
        out[t] = tanhf(a + bias[t]);
    }
}

// ---------------- aggregation: conv1 + FiLM + bias + relu + LayerNorm -> H (fp16) ----------------
// one node per block, 256 threads (=channels)

__device__ inline float wave_red_sum(float v) {
    for (int off = 32; off > 0; off >>= 1) v += __shfl_down(v, off, 64);
    return v;
}

__global__ __launch_bounds__(256) void k_agg1(const f16* __restrict__ Y,
                                              const int* __restrict__ row_ptr,
                                              const int* __restrict__ srcs,
                                              const float* __restrict__ norms,
                                              const float* __restrict__ g1,
                                              const float* __restrict__ be1,
                                              const float* __restrict__ cb1,
                                              f16* __restrict__ H, int nN) {
    int node = blockIdx.x;
    int ch = threadIdx.x;
    int beg = row_ptr[node], end = row_ptr[node + 1];
    const f16* Yc = Y + 256 + ch;  // conv1 cols 256..511
    float acc = 0.f;
    int e = beg;
    for (; e + 4 <= end; e += 4) {
        int s0 = srcs[e], s1 = srcs[e + 1], s2 = srcs[e + 2], s3 = srcs[e + 3];
        float nm0 = norms[e], nm1 = norms[e + 1], nm2 = norms[e + 2], nm3 = norms[e + 3];
        float v0 = (float)Yc[(size_t)s0 * 512];
        float v1 = (float)Yc[(size_t)s1 * 512];
        float v2 = (float)Yc[(size_t)s2 * 512];
        float v3 = (float)Yc[(size_t)s3 * 512];
        acc = fmaf(nm0, v0, acc); acc = fmaf(nm1, v1, acc);
        acc = fmaf(nm2, v2, acc); acc = fmaf(nm3, v3, acc);
    }
    for (; e < end; e++)
        acc = fmaf(norms[e], (float)Yc[(size_t)srcs[e] * 512], acc);

    float v = fmaxf(fmaf(g1[ch], acc, be1[ch] + cb1[ch]), 0.f);

    __shared__ float red[8];
    float sv = wave_red_sum(v);
    float sv2 = wave_red_sum(v * v);
    int wid = ch >> 6, lane = ch & 63;
    if (lane == 0) { red[wid] = sv; red[4 + wid] = sv2; }
    __syncthreads();
    float tot = red[0] + red[1] + red[2] + red[3];
    float tot2 = red[4] + red[5] + red[6] + red[7];
    float mu = tot * (1.f / 256.f);
    float var = tot2 * (1.f / 256.f) - mu * mu;
    float rs = rsqrtf(var + LN_EPS);
    H[(size_t)node * 256 + ch] = (f16)((v - mu) * rs);
}

// ---------------- aggregation: conv2 + FiLM + bias + LayerNorm -> out (fp32) ----------------
// one node per block, 128 threads

__global__ __launch_bounds__(128) void k_agg2(const f16* __restrict__ HW,
                                              const int* __restrict__ row_ptr,
                                              const int* __restrict__ srcs,
                                              const float* __restrict__ norms,
                                              const float* __restrict__ g2,
                                              const float* __restrict__ be2,
                                              const float* __restrict__ cb2,
                                              float* __restrict__ out, int nN) {
    int node = blockIdx.x;
    int ch = threadIdx.x;
    int beg = row_ptr[node], end = row_ptr[node + 1];
    const f16* Yc = HW + ch;
    float acc = 0.f;
    int e = beg;
    for (; e + 4 <= end; e += 4) {
        int s0 = srcs[e], s1 = srcs[e + 1], s2 = srcs[e + 2], s3 = srcs[e + 3];
        float nm0 = norms[e], nm1 = norms[e + 1], nm2 = norms[e + 2], nm3 = norms[e + 3];
        float v0 = (float)Yc[(size_t)s0 * 128];
        float v1 = (float)Yc[(size_t)s1 * 128];
        float v2 = (float)Yc[(size_t)s2 * 128];
        float v3 = (float)Yc[(size_t)s3 * 128];
        acc = fmaf(nm0, v0, acc); acc = fmaf(nm1, v1, acc);
        acc = fmaf(nm2, v2, acc); acc = fmaf(nm3, v3, acc);
    }
    for (; e < end; e++)
        acc = fmaf(norms[e], (float)Yc[(size_t)srcs[e] * 128], acc);

    float v = fmaf(g2[ch], acc, be2[ch] + cb2[ch]);  // no relu on conv2

    __shared__ float red[4];
    float sv = wave_red_sum(v);
    float sv2 = wave_red_sum(v * v);
    int wid = ch >> 6, lane = ch & 63;
    if (lane == 0) { red[wid] = sv; red[2 + wid] = sv2; }
    __syncthreads();
    float tot = red[0] + red[1];
    float tot2 = red[2] + red[3];
    float mu = tot * (1.f / 128.f);
    float var = tot2 * (1.f / 128.f) - mu * mu;
    float rs = rsqrtf(var + LN_EPS);
    out[(size_t)node * 128 + ch] = (v - mu) * rs;
}

// ---------------- host launch ----------------

extern "C" void kernel_launch(void* const* d_in, const int* in_sizes, int n_in,
                              void* d_out, int out_size, void* d_ws, size_t ws_size,
                              hipStream_t stream) {
    const float* x    = (const float*)d_in[0];
    const int*   ei   = (const int*)d_in[1];
    const float* c1w  = (const float*)d_in[2];
    const float* c1b  = (const float*)d_in[3];
    const float* c2w  = (const float*)d_in[4];
    const float* c2b  = (const float*)d_in[5];
    const float* sigw = (const float*)d_in[6];
    const float* sigb = (const float*)d_in[7];
    const float* f1w  = (const float*)d_in[8];
    const float* f1b  = (const float*)d_in[9];
    const float* f2w  = (const float*)d_in[10];
    const float* f2b  = (const float*)d_in[11];
    const float* f3w  = (const float*)d_in[12];
    const float* f3b  = (const float*)d_in[13];
    const float* f4w  = (const float*)d_in[14];
    const float* f4b  = (const float*)d_in[15];
    float* out = (float*)d_out;

    int nN = in_sizes[0] / IN_CH;      // 50000
    int nE = in_sizes[1] / 2;          // 800000
    int nT = nE + nN;                  // 850000

    char* base = (char*)d_ws;
    size_t off = 0;
    auto alloc = [&](size_t bytes) { size_t o = off; off += (bytes + 255) & ~(size_t)255; return o; };

    size_t o_deg    = alloc((size_t)nN * 4);
    size_t o_counts = alloc((size_t)nN * 4);
    size_t o_fillc  = alloc((size_t)nN * 4);
    size_t o_ssig   = alloc(256 * 4);
    size_t zero_bytes = off;                   // zero deg/counts/fillc/s
    size_t o_g1     = alloc(256 * 4);
    size_t o_b1     = alloc(256 * 4);
    size_t o_g2     = alloc(128 * 4);
    size_t o_b2     = alloc(128 * 4);
    size_t o_rowptr = alloc(((size_t)nN + 1) * 4);
    size_t o_dinv   = alloc((size_t)nN * 4);
    size_t o_src    = alloc((size_t)nT * 4);
    size_t o_norm   = alloc((size_t)nT * 4);
    size_t o_wt1    = alloc(512 * 256 * 2);
    size_t o_wt2    = alloc(128 * 256 * 2);
    size_t o_Y      = alloc((size_t)nN * 512 * 2);
    size_t o_H      = alloc((size_t)nN * 256 * 2);
    size_t o_HW     = o_Y;  // alias: Y dead after k_agg1, HW written by k_gemm2 afterwards

    int*   deg    = (int*)(base + o_deg);
    int*   counts = (int*)(base + o_counts);
    int*   fillc  = (int*)(base + o_fillc);
    float* ssig   = (float*)(base + o_ssig);
    float* g1     = (float*)(base + o_g1);
    float* b1     = (float*)(base + o_b1);
    float* g2     = (float*)(base + o_g2);
    float* b2     = (float*)(base + o_b2);
    int*   rowp   = (int*)(base + o_rowptr);
    float* dinv   = (float*)(base + o_dinv);
    int*   srcs   = (int*)(base + o_src);
    float* norms  = (float*)(base + o_norm);
    f16*   Wt1    = (f16*)(base + o_wt1);
    f16*   Wt2    = (f16*)(base + o_wt2);
    f16*   Y      = (f16*)(base + o_Y);
    f16*   H      = (f16*)(base + o_H);
    f16*   HW     = (f16*)(base + o_HW);

    hipMemsetAsync(base, 0, zero_bytes, stream);

    int eb = (nT + 255) / 256;
    k_hist<<<eb, 256, 0, stream>>>(ei, nE, nN, deg, counts);
    k_scan<<<1, 1024, 0, stream>>>(counts, nN, rowp);
    k_dinv<<<(nN + 255) / 256, 256, 0, stream>>>(deg, dinv, nN);
    k_fill<<<eb, 256, 0, stream>>>(ei, nE, nN, dinv, rowp, fillc, srcs, norms);
    k_prepw<<<(512 * 256 + 128 * 256) / 256, 256, 0, stream>>>(sigw, c1w, c2w, Wt1, Wt2);

    int mg = (nN + 31) / 32;
    k_gemm1<<<dim3(2, mg), 256, 0, stream>>>(x, Wt1, Y, nN);
    k_aggsig<<<(nN + 63) / 64, 256, 0, stream>>>(Y, rowp, srcs, norms, sigb, ssig, nN);
    k_fc<<<4, 256, 0, stream>>>(ssig, f1w, f1b, f2w, f2b, f3w, f3b, f4w, f4b, g1, b1, g2, b2);
    k_agg1<<<nN, 256, 0, stream>>>(Y, rowp, srcs, norms, g1, b1, c1b, H, nN);
    k_gemm2<<<dim3(1, mg), 256, 0, stream>>>(H, Wt2, HW, nN);
    k_agg2<<<nN, 128, 0, stream>>>(HW, rowp, srcs, norms, g2, b2, c2b, out, nN);
}

// Round 2
// 576.378 us; speedup vs baseline: 1.2910x; 1.2910x over previous
//
#include <hip/hip_runtime.h>

typedef _Float16 f16;
typedef f16 f16x8 __attribute__((ext_vector_type(8)));
typedef float f32x4 __attribute__((ext_vector_type(4)));

#define IN_CH  256
#define HID    256
#define OUT_CH 128
#define LN_EPS 1e-5f
#define NSLOT  32   // sig partial slots (atomic contention spreading)

// ---------------- graph preprocessing ----------------

__global__ void k_hist(const int* __restrict__ ei, int nE, int nN,
                       int* __restrict__ deg, int* __restrict__ counts) {
    int e = blockIdx.x * blockDim.x + threadIdx.x;
    int total = nE + nN;
    if (e >= total) return;
    int s, d;
    if (e < nE) { s = ei[e]; d = ei[nE + e]; } else { s = d = e - nE; }
    atomicAdd(&deg[s], 1);
    atomicAdd(&counts[d], 1);
}

__global__ __launch_bounds__(1024) void k_scan(const int* __restrict__ counts, int nN,
                                               int* __restrict__ row_ptr) {
    __shared__ int sums[1024];
    int tid = threadIdx.x;
    int per = (nN + 1023) / 1024;
    int start = tid * per;
    int end = start + per; if (end > nN) end = nN;
    int local = 0;
    for (int i = start; i < end; i++) local += counts[i];
    sums[tid] = local;
    __syncthreads();
    for (int off = 1; off < 1024; off <<= 1) {
        int v = (tid >= off) ? sums[tid - off] : 0;
        __syncthreads();
        sums[tid] += v;
        __syncthreads();
    }
    int run = sums[tid] - local;  // exclusive prefix
    for (int i = start; i < end; i++) { row_ptr[i] = run; run += counts[i]; }
    if (tid == 1023) row_ptr[nN] = sums[1023];
}

__global__ void k_dinv(const int* __restrict__ deg, float* __restrict__ dinv, int nN) {
    int i = blockIdx.x * blockDim.x + threadIdx.x;
    if (i < nN) dinv[i] = rsqrtf((float)deg[i]);  // deg >= 1 (self loop)
}

__global__ void k_fill(const int* __restrict__ ei, int nE, int nN,
                       const float* __restrict__ dinv, const int* __restrict__ row_ptr,
                       int* __restrict__ fillc, int* __restrict__ src_sorted,
                       float* __restrict__ norm_sorted) {
    int e = blockIdx.x * blockDim.x + threadIdx.x;
    int total = nE + nN;
    if (e >= total) return;
    int s, d;
    if (e < nE) { s = ei[e]; d = ei[nE + e]; } else { s = d = e - nE; }
    float nm = dinv[s] * dinv[d];
    int pos = row_ptr[d] + atomicAdd(&fillc[d], 1);
    src_sorted[pos] = s;
    norm_sorted[pos] = nm;
}

// ---------------- weight prep: fp32 -> fp16, transposed to [N][K] ----------------

__global__ void k_prepw(const float* __restrict__ sigw, const float* __restrict__ c1w,
                        const float* __restrict__ c2w,
                        f16* __restrict__ Wt1, f16* __restrict__ Wt2) {
    int i = blockIdx.x * 256 + threadIdx.x;
    if (i < 512 * 256) {
        int n = i >> 8, k = i & 255;
        float v = (n < 256) ? sigw[k * 256 + n] : c1w[k * 256 + (n - 256)];
        Wt1[(size_t)n * 256 + k] = (f16)v;
    } else {
        int j = i - 512 * 256;
        if (j < 128 * 256) {
            int n = j >> 8, k = j & 255;
            Wt2[(size_t)n * 256 + k] = (f16)c2w[k * 128 + n];
        }
    }
}

// ---------------- cast x fp32 -> fp16 ----------------

__global__ __launch_bounds__(256) void k_cast(const float* __restrict__ x,
                                              f16* __restrict__ xh, int n) {
    int i = (blockIdx.x * 256 + threadIdx.x) * 8;
    if (i >= n) return;
    float4 a = *(const float4*)(x + i);
    float4 b = *(const float4*)(x + i + 4);
    f16x8 o = { (f16)a.x, (f16)a.y, (f16)a.z, (f16)a.w,
                (f16)b.x, (f16)b.y, (f16)b.z, (f16)b.w };
    *(f16x8*)(xh + i) = o;
}

// ---------------- AX = A * xh  (gather aggregation, wave per node) ----------------
// half-wave per edge: lane = h*32 + sub; sub covers channels sub*8..sub*8+7 (f16x8 = 16B)

__global__ __launch_bounds__(256) void k_aggX(const f16* __restrict__ xh,
                                              const int* __restrict__ rowp,
                                              const int* __restrict__ srcs,
                                              const float* __restrict__ norms,
                                              f16* __restrict__ AX, int nN) {
    int wv = threadIdx.x >> 6;
    int lane = threadIdx.x & 63;
    int node = blockIdx.x * 4 + wv;
    if (node >= nN) return;
    int h = lane >> 5, sub = lane & 31;
    int beg = rowp[node], end = rowp[node + 1];
    float acc[8] = {};
    for (int e0 = beg; e0 < end; e0 += 2) {
        int e = e0 + h;
        bool ok = e < end;
        int eidx = ok ? e : beg;
        int src = srcs[eidx];
        float nm = ok ? norms[eidx] : 0.f;
        f16x8 v = *(const f16x8*)(xh + (size_t)src * 256 + sub * 8);
        #pragma unroll
        for (int j = 0; j < 8; j++) acc[j] = fmaf(nm, (float)v[j], acc[j]);
    }
    #pragma unroll
    for (int j = 0; j < 8; j++) acc[j] += __shfl_xor(acc[j], 32, 64);
    if (lane < 32) {
        f16x8 o;
        #pragma unroll
        for (int j = 0; j < 8; j++) o[j] = (f16)acc[j];
        *(f16x8*)(AX + (size_t)node * 256 + sub * 8) = o;
    }
}

// ---------------- GEMM(sig): relu(AX @ sig_w + sigb) column-summed -> sig_part ----------------
// block = 32 rows x 256 cols (4 waves x 64 cols); never materializes the sig matrix

__global__ __launch_bounds__(256) void k_gemm_sig(const f16* __restrict__ AX,
                                                  const f16* __restrict__ Wt,
                                                  const float* __restrict__ sigb,
                                                  float* __restrict__ sig_part, int M) {
    __shared__ float tile[32][257];
    int t = threadIdx.x;
    int w = t >> 6, lane = t & 63, quad = lane >> 4, l16 = lane & 15;
    int m0 = blockIdx.x * 32;
    int cb = w * 64;
    f32x4 acc[2][4] = {};
    for (int kk = 0; kk < 256; kk += 32) {
        int ka = kk + quad * 8;
        f16x8 a[2];
        #pragma unroll
        for (int ms = 0; ms < 2; ms++) {
            int row = m0 + ms * 16 + l16; if (row >= M) row = M - 1;
            a[ms] = *(const f16x8*)(AX + (size_t)row * 256 + ka);
        }
        #pragma unroll
        for (int ns = 0; ns < 4; ns++) {
            f16x8 b = *(const f16x8*)(Wt + (size_t)(cb + ns * 16 + l16) * 256 + ka);
            acc[0][ns] = __builtin_amdgcn_mfma_f32_16x16x32_f16(a[0], b, acc[0][ns], 0, 0, 0);
            acc[1][ns] = __builtin_amdgcn_mfma_f32_16x16x32_f16(a[1], b, acc[1][ns], 0, 0, 0);
        }
    }
    #pragma unroll
    for (int ms = 0; ms < 2; ms++)
        #pragma unroll
        for (int ns = 0; ns < 4; ns++)
            #pragma unroll
            for (int r = 0; r < 4; r++) {
                int mr = ms * 16 + quad * 4 + r;
                int c = cb + ns * 16 + l16;
                float v = fmaxf(acc[ms][ns][r] + sigb[c], 0.f);
                if (m0 + mr >= M) v = 0.f;
                tile[mr][c] = v;
            }
    __syncthreads();
    float s = 0.f;
    #pragma unroll 8
    for (int r = 0; r < 32; r++) s += tile[r][t];
    atomicAdd(&sig_part[(blockIdx.x & (NSLOT - 1)) * 256 + t], s);
}

// ---------------- FC: reduce slots -> s, then gamma/beta = tanh(s @ W.T + b) ----------------

__global__ __launch_bounds__(256) void k_fc(const float* __restrict__ sig_part,
                                            const float* __restrict__ f1w, const float* __restrict__ f1b,
                                            const float* __restrict__ f2w, const float* __restrict__ f2b,
                                            const float* __restrict__ f3w, const float* __restrict__ f3b,
                                            const float* __restrict__ f4w, const float* __restrict__ f4b,
                                            float* __restrict__ g1, float* __restrict__ b1,
                                            float* __restrict__ g2, float* __restrict__ b2) {
    __shared__ float ss[256];
    int t = threadIdx.x;
    float s = 0.f;
    for (int k = 0; k < NSLOT; k++) s += sig_part[k * 256 + t];
    ss[t] = s;
    __syncthreads();
    float a1 = 0.f, a2 = 0.f, a3 = 0.f, a4 = 0.f;
    const float* w1 = f1w + (size_t)t * 256;
    const float* w2 = f2w + (size_t)t * 256;
    const float* w3 = f3w + (size_t)(t & 127) * 256;
    const float* w4 = f4w + (size_t)(t & 127) * 256;
    for (int j = 0; j < 256; j++) {
        float sj = ss[j];
        a1 = fmaf(w1[j], sj, a1); a2 = fmaf(w2[j], sj, a2);
        a3 = fmaf(w3[j], sj, a3); a4 = fmaf(w4[j], sj, a4);
    }
    g1[t] = tanhf(a1 + f1b[t]);
    b1[t] = tanhf(a2 + f2b[t]);
    if (t < 128) {
        g2[t] = tanhf(a3 + f3b[t]);
        b2[t] = tanhf(a4 + f4b[t]);
    }
}

// ---------------- GEMM(conv1) + FiLM + relu + LayerNorm -> H (fp16) ----------------
// block = 32 rows x 256 cols; LN per row fused via LDS tile

__global__ __launch_bounds__(256) void k_gemm_c1(const f16* __restrict__ AX,
                                                 const f16* __restrict__ Wt,  // conv1 rows
                                                 const float* __restrict__ g1,
                                                 const float* __restrict__ b1,
                                                 const float* __restrict__ c1b,
                                                 f16* __restrict__ H, int M) {
    __shared__ float tile[32][257];
    __shared__ float ps[8][33], ps2[8][33];
    __shared__ float mu_[32], rr_[32];
    int t = threadIdx.x;
    int w = t >> 6, lane = t & 63, quad = lane >> 4, l16 = lane & 15;
    int m0 = blockIdx.x * 32;
    int cb = w * 64;
    f32x4 acc[2][4] = {};
    for (int kk = 0; kk < 256; kk += 32) {
        int ka = kk + quad * 8;
        f16x8 a[2];
        #pragma unroll
        for (int ms = 0; ms < 2; ms++) {
            int row = m0 + ms * 16 + l16; if (row >= M) row = M - 1;
            a[ms] = *(const f16x8*)(AX + (size_t)row * 256 + ka);
        }
        #pragma unroll
        for (int ns = 0; ns < 4; ns++) {
            f16x8 b = *(const f16x8*)(Wt + (size_t)(cb + ns * 16 + l16) * 256 + ka);
            acc[0][ns] = __builtin_amdgcn_mfma_f32_16x16x32_f16(a[0], b, acc[0][ns], 0, 0, 0);
            acc[1][ns] = __builtin_amdgcn_mfma_f32_16x16x32_f16(a[1], b, acc[1][ns], 0, 0, 0);
        }
    }
    #pragma unroll
    for (int ms = 0; ms < 2; ms++)
        #pragma unroll
        for (int ns = 0; ns < 4; ns++)
            #pragma unroll
            for (int r = 0; r < 4; r++) {
                int mr = ms * 16 + quad * 4 + r;
                int c = cb + ns * 16 + l16;
                tile[mr][c] = fmaxf(fmaf(g1[c], acc[ms][ns][r], b1[c] + c1b[c]), 0.f);
            }
    __syncthreads();
    // LN stats: r = t&31 (conflict-free LDS: bank = r+c), seg = t>>5 covers 32 cols
    {
        int r = t & 31, seg = t >> 5;
        float s = 0.f, s2 = 0.f;
        #pragma unroll 8
        for (int c = seg * 32; c < seg * 32 + 32; c++) {
            float xv = tile[r][c];
            s += xv; s2 = fmaf(xv, xv, s2);
        }
        ps[seg][r] = s; ps2[seg][r] = s2;
    }
    __syncthreads();
    if (t < 32) {
        float S = 0.f, S2 = 0.f;
        #pragma unroll
        for (int g = 0; g < 8; g++) { S += ps[g][t]; S2 += ps2[g][t]; }
        float mu = S * (1.f / 256.f);
        mu_[t] = mu;
        rr_[t] = rsqrtf(S2 * (1.f / 256.f) - mu * mu + LN_EPS);
    }
    __syncthreads();
    for (int r = 0; r < 32; r++) {
        int m = m0 + r;
        if (m >= M) break;
        H[(size_t)m * 256 + t] = (f16)((tile[r][t] - mu_[r]) * rr_[r]);
    }
}

// ---------------- GEMM2: HW[M,128] = H[M,256](fp16) @ conv2_w ----------------

__global__ __launch_bounds__(256) void k_gemm2(const f16* __restrict__ H,
                                               const f16* __restrict__ Wt, f16* __restrict__ HW,
                                               int M) {
    int t = threadIdx.x;
    int w = t >> 6, lane = t & 63, quad = lane >> 4, l16 = lane & 15;
    int m0 = blockIdx.x * 32;
    int cb = w * 32;
    f32x4 acc[2][2] = {};
    for (int kk = 0; kk < 256; kk += 32) {
        int ka = kk + quad * 8;
        f16x8 a[2];
        #pragma unroll
        for (int ms = 0; ms < 2; ms++) {
            int row = m0 + ms * 16 + l16; if (row >= M) row = M - 1;
            a[ms] = *(const f16x8*)(H + (size_t)row * 256 + ka);
        }
        #pragma unroll
        for (int ns = 0; ns < 2; ns++) {
            f16x8 b = *(const f16x8*)(Wt + (size_t)(cb + ns * 16 + l16) * 256 + ka);
            acc[0][ns] = __builtin_amdgcn_mfma_f32_16x16x32_f16(a[0], b, acc[0][ns], 0, 0, 0);
            acc[1][ns] = __builtin_amdgcn_mfma_f32_16x16x32_f16(a[1], b, acc[1][ns], 0, 0, 0);
        }
    }
    #pragma unroll
    for (int ms = 0; ms < 2; ms++)
        #pragma unroll
        for (int ns = 0; ns < 2; ns++)
            #pragma unroll
            for (int r = 0; r < 4; r++) {
                int m = m0 + ms * 16 + quad * 4 + r;
                if (m < M) HW[(size_t)m * 128 + cb + ns * 16 + l16] = (f16)acc[ms][ns][r];
            }
}

// ---------------- agg2: out = LN(g2 * (A*HW) + b2 + c2b)  (wave per node) ----------------
// quarter-wave per edge: lane = q*16 + sub; sub covers channels sub*8..sub*8+7

__global__ __launch_bounds__(256) void k_agg2(const f16* __restrict__ HW,
                                              const int* __restrict__ rowp,
                                              const int* __restrict__ srcs,
                                              const float* __restrict__ norms,
                                              const float* __restrict__ g2,
                                              const float* __restrict__ b2,
                                              const float* __restrict__ c2b,
                                              float* __restrict__ out, int nN) {
    int wv = threadIdx.x >> 6;
    int lane = threadIdx.x & 63;
    int node = blockIdx.x * 4 + wv;
    if (node >= nN) return;
    int q = lane >> 4, sub = lane & 15;
    int beg = rowp[node], end = rowp[node + 1];
    float acc[8] = {};
    for (int e0 = beg; e0 < end; e0 += 4) {
        int e = e0 + q;
        bool ok = e < end;
        int eidx = ok ? e : beg;
        int src = srcs[eidx];
        float nm = ok ? norms[eidx] : 0.f;
        f16x8 v = *(const f16x8*)(HW + (size_t)src * 128 + sub * 8);
        #pragma unroll
        for (int j = 0; j < 8; j++) acc[j] = fmaf(nm, (float)v[j], acc[j]);
    }
    #pragma unroll
    for (int j = 0; j < 8; j++) {
        acc[j] += __shfl_xor(acc[j], 16, 64);
        acc[j] += __shfl_xor(acc[j], 32, 64);
    }
    int ch = sub * 8;
    float vfin[8];
    float s = 0.f, s2 = 0.f;
    #pragma unroll
    for (int j = 0; j < 8; j++) {
        float v = fmaf(g2[ch + j], acc[j], b2[ch + j] + c2b[ch + j]);
        vfin[j] = v;
        s += v; s2 = fmaf(v, v, s2);
    }
    #pragma unroll
    for (int off = 1; off < 16; off <<= 1) {
        s += __shfl_xor(s, off, 64);
        s2 += __shfl_xor(s2, off, 64);
    }
    float mu = s * (1.f / 128.f);
    float rr = rsqrtf(s2 * (1.f / 128.f) - mu * mu + LN_EPS);
    if (q == 0) {
        float4 o0 = { (vfin[0] - mu) * rr, (vfin[1] - mu) * rr,
                      (vfin[2] - mu) * rr, (vfin[3] - mu) * rr };
        float4 o1 = { (vfin[4] - mu) * rr, (vfin[5] - mu) * rr,
                      (vfin[6] - mu) * rr, (vfin[7] - mu) * rr };
        float* dst = out + (size_t)node * 128 + ch;
        *(float4*)dst = o0;
        *(float4*)(dst + 4) = o1;
    }
}

// ---------------- host launch ----------------

extern "C" void kernel_launch(void* const* d_in, const int* in_sizes, int n_in,
                              void* d_out, int out_size, void* d_ws, size_t ws_size,
                              hipStream_t stream) {
    const float* x    = (const float*)d_in[0];
    const int*   ei   = (const int*)d_in[1];
    const float* c1w  = (const float*)d_in[2];
    const float* c1b  = (const float*)d_in[3];
    const float* c2w  = (const float*)d_in[4];
    const float* c2b  = (const float*)d_in[5];
    const float* sigw = (const float*)d_in[6];
    const float* sigb = (const float*)d_in[7];
    const float* f1w  = (const float*)d_in[8];
    const float* f1b  = (const float*)d_in[9];
    const float* f2w  = (const float*)d_in[10];
    const float* f2b  = (const float*)d_in[11];
    const float* f3w  = (const float*)d_in[12];
    const float* f3b  = (const float*)d_in[13];
    const float* f4w  = (const float*)d_in[14];
    const float* f4b  = (const float*)d_in[15];
    float* out = (float*)d_out;

    int nN = in_sizes[0] / IN_CH;      // 50000
    int nE = in_sizes[1] / 2;          // 800000
    int nT = nE + nN;                  // 850000

    char* base = (char*)d_ws;
    size_t off = 0;
    auto alloc = [&](size_t bytes) { size_t o = off; off += (bytes + 255) & ~(size_t)255; return o; };

    size_t o_deg    = alloc((size_t)nN * 4);
    size_t o_counts = alloc((size_t)nN * 4);
    size_t o_fillc  = alloc((size_t)nN * 4);
    size_t o_spart  = alloc((size_t)NSLOT * 256 * 4);
    size_t zero_bytes = off;                   // zero deg/counts/fillc/sig_part
    size_t o_g1     = alloc(256 * 4);
    size_t o_b1     = alloc(256 * 4);
    size_t o_g2     = alloc(128 * 4);
    size_t o_b2     = alloc(128 * 4);
    size_t o_rowptr = alloc(((size_t)nN + 1) * 4);
    size_t o_dinv   = alloc((size_t)nN * 4);
    size_t o_src    = alloc((size_t)nT * 4);
    size_t o_norm   = alloc((size_t)nT * 4);
    size_t o_wt1    = alloc(512 * 256 * 2);
    size_t o_wt2    = alloc(128 * 256 * 2);
    size_t o_xh     = alloc((size_t)nN * 256 * 2);
    size_t o_AX     = alloc((size_t)nN * 256 * 2);
    size_t o_H      = alloc((size_t)nN * 256 * 2);
    size_t o_HW     = alloc((size_t)nN * 128 * 2);

    int*   deg    = (int*)(base + o_deg);
    int*   counts = (int*)(base + o_counts);
    int*   fillc  = (int*)(base + o_fillc);
    float* spart  = (float*)(base + o_spart);
    float* g1     = (float*)(base + o_g1);
    float* b1     = (float*)(base + o_b1);
    float* g2     = (float*)(base + o_g2);
    float* b2     = (float*)(base + o_b2);
    int*   rowp   = (int*)(base + o_rowptr);
    float* dinv   = (float*)(base + o_dinv);
    int*   srcs   = (int*)(base + o_src);
    float* norms  = (float*)(base + o_norm);
    f16*   Wt1    = (f16*)(base + o_wt1);
    f16*   Wt2    = (f16*)(base + o_wt2);
    f16*   xh     = (f16*)(base + o_xh);
    f16*   AX     = (f16*)(base + o_AX);
    f16*   H      = (f16*)(base + o_H);
    f16*   HW     = (f16*)(base + o_HW);

    hipMemsetAsync(base, 0, zero_bytes, stream);

    int eb = (nT + 255) / 256;
    k_hist<<<eb, 256, 0, stream>>>(ei, nE, nN, deg, counts);
    k_scan<<<1, 1024, 0, stream>>>(counts, nN, rowp);
    k_dinv<<<(nN + 255) / 256, 256, 0, stream>>>(deg, dinv, nN);
    k_fill<<<eb, 256, 0, stream>>>(ei, nE, nN, dinv, rowp, fillc, srcs, norms);
    k_prepw<<<(512 * 256 + 128 * 256) / 256, 256, 0, stream>>>(sigw, c1w, c2w, Wt1, Wt2);
    k_cast<<<(nN * IN_CH + 2047) / 2048, 256, 0, stream>>>(x, xh, nN * IN_CH);

    int nb4 = (nN + 3) / 4;
    int mg = (nN + 31) / 32;
    k_aggX<<<nb4, 256, 0, stream>>>(xh, rowp, srcs, norms, AX, nN);
    k_gemm_sig<<<mg, 256, 0, stream>>>(AX, Wt1, sigb, spart, nN);
    k_fc<<<1, 256, 0, stream>>>(spart, f1w, f1b, f2w, f2b, f3w, f3b, f4w, f4b, g1, b1, g2, b2);
    k_gemm_c1<<<mg, 256, 0, stream>>>(AX, Wt1 + 256 * 256, g1, b1, c1b, H, nN);
    k_gemm2<<<mg, 256, 0, stream>>>(H, Wt2, HW, nN);
    k_agg2<<<nb4, 256, 0, stream>>>(HW, rowp, srcs, norms, g2, b2, c2b, out, nN);
}

// Round 3
// 504.305 us; speedup vs baseline: 1.4755x; 1.1429x over previous
//
#include <hip/hip_runtime.h>

typedef _Float16 f16;
typedef f16 f16x8 __attribute__((ext_vector_type(8)));
typedef float f32x4 __attribute__((ext_vector_type(4)));

#define IN_CH  256
#define HID    256
#define OUT_CH 128
#define LN_EPS 1e-5f
#define NSLOT  32   // sig partial slots (atomic contention spreading)

// ---------------- graph preprocessing ----------------

__global__ void k_hist(const int* __restrict__ ei, int nE, int nN,
                       int* __restrict__ deg, int* __restrict__ counts) {
    int e = blockIdx.x * blockDim.x + threadIdx.x;
    int total = nE + nN;
    if (e >= total) return;
    int s, d;
    if (e < nE) { s = ei[e]; d = ei[nE + e]; } else { s = d = e - nE; }
    atomicAdd(&deg[s], 1);
    atomicAdd(&counts[d], 1);
}

// CSR slice allocation without a global scan: wave-prefix + one atomic per wave.
// Row starts are NOT monotone in node id — harmless, each node owns [start, start+cnt).
// dinv fused in (same node-indexed pass).
__global__ __launch_bounds__(256) void k_alloc(const int* __restrict__ counts,
                                               const int* __restrict__ deg,
                                               int* __restrict__ rowstart,
                                               float* __restrict__ dinv,
                                               int* __restrict__ ctr, int nN) {
    int i = blockIdx.x * 256 + threadIdx.x;
    int lane = threadIdx.x & 63;
    int c = (i < nN) ? counts[i] : 0;
    int p = c;
    #pragma unroll
    for (int off = 1; off < 64; off <<= 1) {
        int v = __shfl_up(p, off, 64);
        if (lane >= off) p += v;
    }
    int tot = __shfl(p, 63, 64);
    int base = 0;
    if (lane == 0) base = atomicAdd(ctr, tot);
    base = __shfl(base, 0, 64);
    if (i < nN) {
        rowstart[i] = base + p - c;
        dinv[i] = rsqrtf((float)deg[i]);  // deg >= 1 (self loop)
    }
}

__global__ void k_fill(const int* __restrict__ ei, int nE, int nN,
                       const float* __restrict__ dinv, const int* __restrict__ rowstart,
                       int* __restrict__ fillc, int* __restrict__ src_sorted,
                       float* __restrict__ norm_sorted) {
    int e = blockIdx.x * blockDim.x + threadIdx.x;
    int total = nE + nN;
    if (e >= total) return;
    int s, d;
    if (e < nE) { s = ei[e]; d = ei[nE + e]; } else { s = d = e - nE; }
    float nm = dinv[s] * dinv[d];
    int pos = rowstart[d] + atomicAdd(&fillc[d], 1);
    src_sorted[pos] = s;
    norm_sorted[pos] = nm;
}

// ---------------- weight prep: fp32 -> fp16, transposed to [N][K] ----------------

__global__ void k_prepw(const float* __restrict__ sigw, const float* __restrict__ c1w,
                        const float* __restrict__ c2w,
                        f16* __restrict__ Wt1, f16* __restrict__ Wt2) {
    int i = blockIdx.x * 256 + threadIdx.x;
    if (i < 512 * 256) {
        int n = i >> 8, k = i & 255;
        float v = (n < 256) ? sigw[k * 256 + n] : c1w[k * 256 + (n - 256)];
        Wt1[(size_t)n * 256 + k] = (f16)v;
    } else {
        int j = i - 512 * 256;
        if (j < 128 * 256) {
            int n = j >> 8, k = j & 255;
            Wt2[(size_t)n * 256 + k] = (f16)c2w[k * 128 + n];
        }
    }
}

// ---------------- cast x fp32 -> fp16 ----------------

__global__ __launch_bounds__(256) void k_cast(const float* __restrict__ x,
                                              f16* __restrict__ xh, int n) {
    int i = (blockIdx.x * 256 + threadIdx.x) * 8;
    if (i >= n) return;
    float4 a = *(const float4*)(x + i);
    float4 b = *(const float4*)(x + i + 4);
    f16x8 o = { (f16)a.x, (f16)a.y, (f16)a.z, (f16)a.w,
                (f16)b.x, (f16)b.y, (f16)b.z, (f16)b.w };
    *(f16x8*)(xh + i) = o;
}

// ---------------- AX = A * xh  (gather aggregation, wave per node) ----------------
// half-wave per edge: lane = h*32 + sub; sub covers channels sub*8..sub*8+7 (f16x8 = 16B)
// unrolled x2: 4 gathers in flight per wave, two independent acc chains

__global__ __launch_bounds__(256) void k_aggX(const f16* __restrict__ xh,
                                              const int* __restrict__ rowstart,
                                              const int* __restrict__ counts,
                                              const int* __restrict__ srcs,
                                              const float* __restrict__ norms,
                                              f16* __restrict__ AX, int nN) {
    int wv = threadIdx.x >> 6;
    int lane = threadIdx.x & 63;
    int node = blockIdx.x * 4 + wv;
    if (node >= nN) return;
    int h = lane >> 5, sub = lane & 31;
    int beg = rowstart[node];
    int end = beg + counts[node];
    float acc0[8] = {}, acc1[8] = {};
    for (int e0 = beg; e0 < end; e0 += 4) {
        int ea = e0 + h, eb = e0 + 2 + h;
        bool oka = ea < end, okb = eb < end;
        int ia = oka ? ea : beg;
        int ib = okb ? eb : beg;
        int sa = srcs[ia], sb = srcs[ib];
        float na = oka ? norms[ia] : 0.f;
        float nb = okb ? norms[ib] : 0.f;
        f16x8 va = *(const f16x8*)(xh + (size_t)sa * 256 + sub * 8);
        f16x8 vb = *(const f16x8*)(xh + (size_t)sb * 256 + sub * 8);
        #pragma unroll
        for (int j = 0; j < 8; j++) {
            acc0[j] = fmaf(na, (float)va[j], acc0[j]);
            acc1[j] = fmaf(nb, (float)vb[j], acc1[j]);
        }
    }
    #pragma unroll
    for (int j = 0; j < 8; j++) {
        acc0[j] += acc1[j];
        acc0[j] += __shfl_xor(acc0[j], 32, 64);
    }
    if (lane < 32) {
        f16x8 o;
        #pragma unroll
        for (int j = 0; j < 8; j++) o[j] = (f16)acc0[j];
        *(f16x8*)(AX + (size_t)node * 256 + sub * 8) = o;
    }
}

// ---------------- GEMM(sig): relu(AX @ sig_w + sigb) column-summed -> sig_part ----------------
// block = 32 rows x 256 cols (4 waves x 64 cols); never materializes the sig matrix

__global__ __launch_bounds__(256) void k_gemm_sig(const f16* __restrict__ AX,
                                                  const f16* __restrict__ Wt,
                                                  const float* __restrict__ sigb,
                                                  float* __restrict__ sig_part, int M) {
    __shared__ float tile[32][257];
    int t = threadIdx.x;
    int w = t >> 6, lane = t & 63, quad = lane >> 4, l16 = lane & 15;
    int m0 = blockIdx.x * 32;
    int cb = w * 64;
    f32x4 acc[2][4] = {};
    for (int kk = 0; kk < 256; kk += 32) {
        int ka = kk + quad * 8;
        f16x8 a[2];
        #pragma unroll
        for (int ms = 0; ms < 2; ms++) {
            int row = m0 + ms * 16 + l16; if (row >= M) row = M - 1;
            a[ms] = *(const f16x8*)(AX + (size_t)row * 256 + ka);
        }
        #pragma unroll
        for (int ns = 0; ns < 4; ns++) {
            f16x8 b = *(const f16x8*)(Wt + (size_t)(cb + ns * 16 + l16) * 256 + ka);
            acc[0][ns] = __builtin_amdgcn_mfma_f32_16x16x32_f16(a[0], b, acc[0][ns], 0, 0, 0);
            acc[1][ns] = __builtin_amdgcn_mfma_f32_16x16x32_f16(a[1], b, acc[1][ns], 0, 0, 0);
        }
    }
    #pragma unroll
    for (int ms = 0; ms < 2; ms++)
        #pragma unroll
        for (int ns = 0; ns < 4; ns++)
            #pragma unroll
            for (int r = 0; r < 4; r++) {
                int mr = ms * 16 + quad * 4 + r;
                int c = cb + ns * 16 + l16;
                float v = fmaxf(acc[ms][ns][r] + sigb[c], 0.f);
                if (m0 + mr >= M) v = 0.f;
                tile[mr][c] = v;
            }
    __syncthreads();
    float s = 0.f;
    #pragma unroll 8
    for (int r = 0; r < 32; r++) s += tile[r][t];
    atomicAdd(&sig_part[(blockIdx.x & (NSLOT - 1)) * 256 + t], s);
}

// ---------------- FC: reduce slots -> s, then gamma/beta = tanh(s @ W.T + b) ----------------

__global__ __launch_bounds__(256) void k_fc(const float* __restrict__ sig_part,
                                            const float* __restrict__ f1w, const float* __restrict__ f1b,
                                            const float* __restrict__ f2w, const float* __restrict__ f2b,
                                            const float* __restrict__ f3w, const float* __restrict__ f3b,
                                            const float* __restrict__ f4w, const float* __restrict__ f4b,
                                            float* __restrict__ g1, float* __restrict__ b1,
                                            float* __restrict__ g2, float* __restrict__ b2) {
    __shared__ float ss[256];
    int t = threadIdx.x;
    float s = 0.f;
    for (int k = 0; k < NSLOT; k++) s += sig_part[k * 256 + t];
    ss[t] = s;
    __syncthreads();
    float a1 = 0.f, a2 = 0.f, a3 = 0.f, a4 = 0.f;
    const float* w1 = f1w + (size_t)t * 256;
    const float* w2 = f2w + (size_t)t * 256;
    const float* w3 = f3w + (size_t)(t & 127) * 256;
    const float* w4 = f4w + (size_t)(t & 127) * 256;
    for (int j = 0; j < 256; j++) {
        float sj = ss[j];
        a1 = fmaf(w1[j], sj, a1); a2 = fmaf(w2[j], sj, a2);
        a3 = fmaf(w3[j], sj, a3); a4 = fmaf(w4[j], sj, a4);
    }
    g1[t] = tanhf(a1 + f1b[t]);
    b1[t] = tanhf(a2 + f2b[t]);
    if (t < 128) {
        g2[t] = tanhf(a3 + f3b[t]);
        b2[t] = tanhf(a4 + f4b[t]);
    }
}

// ---------------- GEMM(conv1) + FiLM + relu + LayerNorm -> H (fp16) ----------------
// block = 32 rows x 256 cols; LN per row fused via LDS tile

__global__ __launch_bounds__(256) void k_gemm_c1(const f16* __restrict__ AX,
                                                 const f16* __restrict__ Wt,  // conv1 rows
                                                 const float* __restrict__ g1,
                                                 const float* __restrict__ b1,
                                                 const float* __restrict__ c1b,
                                                 f16* __restrict__ H, int M) {
    __shared__ float tile[32][257];
    __shared__ float ps[8][33], ps2[8][33];
    __shared__ float mu_[32], rr_[32];
    int t = threadIdx.x;
    int w = t >> 6, lane = t & 63, quad = lane >> 4, l16 = lane & 15;
    int m0 = blockIdx.x * 32;
    int cb = w * 64;
    f32x4 acc[2][4] = {};
    for (int kk = 0; kk < 256; kk += 32) {
        int ka = kk + quad * 8;
        f16x8 a[2];
        #pragma unroll
        for (int ms = 0; ms < 2; ms++) {
            int row = m0 + ms * 16 + l16; if (row >= M) row = M - 1;
            a[ms] = *(const f16x8*)(AX + (size_t)row * 256 + ka);
        }
        #pragma unroll
        for (int ns = 0; ns < 4; ns++) {
            f16x8 b = *(const f16x8*)(Wt + (size_t)(cb + ns * 16 + l16) * 256 + ka);
            acc[0][ns] = __builtin_amdgcn_mfma_f32_16x16x32_f16(a[0], b, acc[0][ns], 0, 0, 0);
            acc[1][ns] = __builtin_amdgcn_mfma_f32_16x16x32_f16(a[1], b, acc[1][ns], 0, 0, 0);
        }
    }
    #pragma unroll
    for (int ms = 0; ms < 2; ms++)
        #pragma unroll
        for (int ns = 0; ns < 4; ns++)
            #pragma unroll
            for (int r = 0; r < 4; r++) {
                int mr = ms * 16 + quad * 4 + r;
                int c = cb + ns * 16 + l16;
                tile[mr][c] = fmaxf(fmaf(g1[c], acc[ms][ns][r], b1[c] + c1b[c]), 0.f);
            }
    __syncthreads();
    // LN stats: r = t&31 (conflict-free LDS: bank = r+c), seg = t>>5 covers 32 cols
    {
        int r = t & 31, seg = t >> 5;
        float s = 0.f, s2 = 0.f;
        #pragma unroll 8
        for (int c = seg * 32; c < seg * 32 + 32; c++) {
            float xv = tile[r][c];
            s += xv; s2 = fmaf(xv, xv, s2);
        }
        ps[seg][r] = s; ps2[seg][r] = s2;
    }
    __syncthreads();
    if (t < 32) {
        float S = 0.f, S2 = 0.f;
        #pragma unroll
        for (int g = 0; g < 8; g++) { S += ps[g][t]; S2 += ps2[g][t]; }
        float mu = S * (1.f / 256.f);
        mu_[t] = mu;
        rr_[t] = rsqrtf(S2 * (1.f / 256.f) - mu * mu + LN_EPS);
    }
    __syncthreads();
    for (int r = 0; r < 32; r++) {
        int m = m0 + r;
        if (m >= M) break;
        H[(size_t)m * 256 + t] = (f16)((tile[r][t] - mu_[r]) * rr_[r]);
    }
}

// ---------------- GEMM2: HW[M,128] = H[M,256](fp16) @ conv2_w ----------------

__global__ __launch_bounds__(256) void k_gemm2(const f16* __restrict__ H,
                                               const f16* __restrict__ Wt, f16* __restrict__ HW,
                                               int M) {
    int t = threadIdx.x;
    int w = t >> 6, lane = t & 63, quad = lane >> 4, l16 = lane & 15;
    int m0 = blockIdx.x * 32;
    int cb = w * 32;
    f32x4 acc[2][2] = {};
    for (int kk = 0; kk < 256; kk += 32) {
        int ka = kk + quad * 8;
        f16x8 a[2];
        #pragma unroll
        for (int ms = 0; ms < 2; ms++) {
            int row = m0 + ms * 16 + l16; if (row >= M) row = M - 1;
            a[ms] = *(const f16x8*)(H + (size_t)row * 256 + ka);
        }
        #pragma unroll
        for (int ns = 0; ns < 2; ns++) {
            f16x8 b = *(const f16x8*)(Wt + (size_t)(cb + ns * 16 + l16) * 256 + ka);
            acc[0][ns] = __builtin_amdgcn_mfma_f32_16x16x32_f16(a[0], b, acc[0][ns], 0, 0, 0);
            acc[1][ns] = __builtin_amdgcn_mfma_f32_16x16x32_f16(a[1], b, acc[1][ns], 0, 0, 0);
        }
    }
    #pragma unroll
    for (int ms = 0; ms < 2; ms++)
        #pragma unroll
        for (int ns = 0; ns < 2; ns++)
            #pragma unroll
            for (int r = 0; r < 4; r++) {
                int m = m0 + ms * 16 + quad * 4 + r;
                if (m < M) HW[(size_t)m * 128 + cb + ns * 16 + l16] = (f16)acc[ms][ns][r];
            }
}

// ---------------- agg2: out = LN(g2 * (A*HW) + b2 + c2b)  (wave per node) ----------------
// quarter-wave per edge: lane = q*16 + sub; sub covers channels sub*8..sub*8+7
// unrolled x2: 8 gathers in flight per wave

__global__ __launch_bounds__(256) void k_agg2(const f16* __restrict__ HW,
                                              const int* __restrict__ rowstart,
                                              const int* __restrict__ counts,
                                              const int* __restrict__ srcs,
                                              const float* __restrict__ norms,
                                              const float* __restrict__ g2,
                                              const float* __restrict__ b2,
                                              const float* __restrict__ c2b,
                                              float* __restrict__ out, int nN) {
    int wv = threadIdx.x >> 6;
    int lane = threadIdx.x & 63;
    int node = blockIdx.x * 4 + wv;
    if (node >= nN) return;
    int q = lane >> 4, sub = lane & 15;
    int beg = rowstart[node];
    int end = beg + counts[node];
    float acc0[8] = {}, acc1[8] = {};
    for (int e0 = beg; e0 < end; e0 += 8) {
        int ea = e0 + q, eb = e0 + 4 + q;
        bool oka = ea < end, okb = eb < end;
        int ia = oka ? ea : beg;
        int ib = okb ? eb : beg;
        int sa = srcs[ia], sb = srcs[ib];
        float na = oka ? norms[ia] : 0.f;
        float nb = okb ? norms[ib] : 0.f;
        f16x8 va = *(const f16x8*)(HW + (size_t)sa * 128 + sub * 8);
        f16x8 vb = *(const f16x8*)(HW + (size_t)sb * 128 + sub * 8);
        #pragma unroll
        for (int j = 0; j < 8; j++) {
            acc0[j] = fmaf(na, (float)va[j], acc0[j]);
            acc1[j] = fmaf(nb, (float)vb[j], acc1[j]);
        }
    }
    #pragma unroll
    for (int j = 0; j < 8; j++) {
        acc0[j] += acc1[j];
        acc0[j] += __shfl_xor(acc0[j], 16, 64);
        acc0[j] += __shfl_xor(acc0[j], 32, 64);
    }
    int ch = sub * 8;
    float vfin[8];
    float s = 0.f, s2 = 0.f;
    #pragma unroll
    for (int j = 0; j < 8; j++) {
        float v = fmaf(g2[ch + j], acc0[j], b2[ch + j] + c2b[ch + j]);
        vfin[j] = v;
        s += v; s2 = fmaf(v, v, s2);
    }
    #pragma unroll
    for (int off = 1; off < 16; off <<= 1) {
        s += __shfl_xor(s, off, 64);
        s2 += __shfl_xor(s2, off, 64);
    }
    float mu = s * (1.f / 128.f);
    float rr = rsqrtf(s2 * (1.f / 128.f) - mu * mu + LN_EPS);
    if (q == 0) {
        float4 o0 = { (vfin[0] - mu) * rr, (vfin[1] - mu) * rr,
                      (vfin[2] - mu) * rr, (vfin[3] - mu) * rr };
        float4 o1 = { (vfin[4] - mu) * rr, (vfin[5] - mu) * rr,
                      (vfin[6] - mu) * rr, (vfin[7] - mu) * rr };
        float* dst = out + (size_t)node * 128 + ch;
        *(float4*)dst = o0;
        *(float4*)(dst + 4) = o1;
    }
}

// ---------------- host launch ----------------

extern "C" void kernel_launch(void* const* d_in, const int* in_sizes, int n_in,
                              void* d_out, int out_size, void* d_ws, size_t ws_size,
                              hipStream_t stream) {
    const float* x    = (const float*)d_in[0];
    const int*   ei   = (const int*)d_in[1];
    const float* c1w  = (const float*)d_in[2];
    const float* c1b  = (const float*)d_in[3];
    const float* c2w  = (const float*)d_in[4];
    const float* c2b  = (const float*)d_in[5];
    const float* sigw = (const float*)d_in[6];
    const float* sigb = (const float*)d_in[7];
    const float* f1w  = (const float*)d_in[8];
    const float* f1b  = (const float*)d_in[9];
    const float* f2w  = (const float*)d_in[10];
    const float* f2b  = (const float*)d_in[11];
    const float* f3w  = (const float*)d_in[12];
    const float* f3b  = (const float*)d_in[13];
    const float* f4w  = (const float*)d_in[14];
    const float* f4b  = (const float*)d_in[15];
    float* out = (float*)d_out;

    int nN = in_sizes[0] / IN_CH;      // 50000
    int nE = in_sizes[1] / 2;          // 800000
    int nT = nE + nN;                  // 850000

    char* base = (char*)d_ws;
    size_t off = 0;
    auto alloc = [&](size_t bytes) { size_t o = off; off += (bytes + 255) & ~(size_t)255; return o; };

    size_t o_deg    = alloc((size_t)nN * 4);
    size_t o_counts = alloc((size_t)nN * 4);
    size_t o_fillc  = alloc((size_t)nN * 4);
    size_t o_spart  = alloc((size_t)NSLOT * 256 * 4);
    size_t o_ctr    = alloc(256);
    size_t zero_bytes = off;                   // zero deg/counts/fillc/sig_part/ctr
    size_t o_g1     = alloc(256 * 4);
    size_t o_b1     = alloc(256 * 4);
    size_t o_g2     = alloc(128 * 4);
    size_t o_b2     = alloc(128 * 4);
    size_t o_rowst  = alloc((size_t)nN * 4);
    size_t o_dinv   = alloc((size_t)nN * 4);
    size_t o_src    = alloc((size_t)nT * 4);
    size_t o_norm   = alloc((size_t)nT * 4);
    size_t o_wt1    = alloc(512 * 256 * 2);
    size_t o_wt2    = alloc(128 * 256 * 2);
    size_t o_xh     = alloc((size_t)nN * 256 * 2);
    size_t o_AX     = alloc((size_t)nN * 256 * 2);
    size_t o_H      = alloc((size_t)nN * 256 * 2);
    size_t o_HW     = alloc((size_t)nN * 128 * 2);

    int*   deg    = (int*)(base + o_deg);
    int*   counts = (int*)(base + o_counts);
    int*   fillc  = (int*)(base + o_fillc);
    float* spart  = (float*)(base + o_spart);
    int*   ctr    = (int*)(base + o_ctr);
    float* g1     = (float*)(base + o_g1);
    float* b1     = (float*)(base + o_b1);
    float* g2     = (float*)(base + o_g2);
    float* b2     = (float*)(base + o_b2);
    int*   rowst  = (int*)(base + o_rowst);
    float* dinv   = (float*)(base + o_dinv);
    int*   srcs   = (int*)(base + o_src);
    float* norms  = (float*)(base + o_norm);
    f16*   Wt1    = (f16*)(base + o_wt1);
    f16*   Wt2    = (f16*)(base + o_wt2);
    f16*   xh     = (f16*)(base + o_xh);
    f16*   AX     = (f16*)(base + o_AX);
    f16*   H      = (f16*)(base + o_H);
    f16*   HW     = (f16*)(base + o_HW);

    hipMemsetAsync(base, 0, zero_bytes, stream);

    int eb = (nT + 255) / 256;
    k_hist<<<eb, 256, 0, stream>>>(ei, nE, nN, deg, counts);
    k_alloc<<<(nN + 255) / 256, 256, 0, stream>>>(counts, deg, rowst, dinv, ctr, nN);
    k_fill<<<eb, 256, 0, stream>>>(ei, nE, nN, dinv, rowst, fillc, srcs, norms);
    k_prepw<<<(512 * 256 + 128 * 256) / 256, 256, 0, stream>>>(sigw, c1w, c2w, Wt1, Wt2);
    k_cast<<<(nN * IN_CH + 2047) / 2048, 256, 0, stream>>>(x, xh, nN * IN_CH);

    int nb4 = (nN + 3) / 4;
    int mg = (nN + 31) / 32;
    k_aggX<<<nb4, 256, 0, stream>>>(xh, rowst, counts, srcs, norms, AX, nN);
    k_gemm_sig<<<mg, 256, 0, stream>>>(AX, Wt1, sigb, spart, nN);
    k_fc<<<1, 256, 0, stream>>>(spart, f1w, f1b, f2w, f2b, f3w, f3b, f4w, f4b, g1, b1, g2, b2);
    k_gemm_c1<<<mg, 256, 0, stream>>>(AX, Wt1 + 256 * 256, g1, b1, c1b, H, nN);
    k_gemm2<<<mg, 256, 0, stream>>>(H, Wt2, HW, nN);
    k_agg2<<<nb4, 256, 0, stream>>>(HW, rowst, counts, srcs, norms, g2, b2, c2b, out, nN);
}

// Round 4
// 478.824 us; speedup vs baseline: 1.5540x; 1.0532x over previous
//
#include <hip/hip_runtime.h>

typedef _Float16 f16;
typedef f16 f16x8 __attribute__((ext_vector_type(8)));
typedef float f32x4 __attribute__((ext_vector_type(4)));
typedef unsigned short u16;

#define IN_CH  256
#define HID    256
#define OUT_CH 128
#define LN_EPS 1e-5f
#define NSLOT  32   // sig partial slots (atomic contention spreading)

// ---------------- fused pre-pass: cast(x->f16) | edge histogram | weight prep ----------------
// interleaved bid&1 striping so latency-bound hist blocks overlap BW-bound cast blocks

__global__ __launch_bounds__(256) void k_pre0(const float* __restrict__ x, f16* __restrict__ xh, int nelem,
                                              const int* __restrict__ ei, int nE, int nN,
                                              int* __restrict__ deg, int* __restrict__ counts,
                                              const float* __restrict__ sigw, const float* __restrict__ c1w,
                                              const float* __restrict__ c2w,
                                              f16* __restrict__ Wt1, f16* __restrict__ Wt2,
                                              int nCast, int nHist) {
    int bid = blockIdx.x;
    int half = bid >> 1;
    if ((bid & 1) == 0) {
        if (half >= nCast) return;
        int i = (half * 256 + threadIdx.x) * 8;
        if (i >= nelem) return;
        float4 a = *(const float4*)(x + i);
        float4 b = *(const float4*)(x + i + 4);
        f16x8 o = { (f16)a.x, (f16)a.y, (f16)a.z, (f16)a.w,
                    (f16)b.x, (f16)b.y, (f16)b.z, (f16)b.w };
        *(f16x8*)(xh + i) = o;
    } else if (half < nHist) {
        int e = half * 256 + threadIdx.x;
        int total = nE + nN;
        if (e >= total) return;
        int s, d;
        if (e < nE) { s = ei[e]; d = ei[nE + e]; } else { s = d = e - nE; }
        atomicAdd(&deg[s], 1);
        atomicAdd(&counts[d], 1);
    } else {
        int i = (half - nHist) * 256 + threadIdx.x;
        if (i < 512 * 256) {
            int n = i >> 8, k = i & 255;
            float v = (n < 256) ? sigw[k * 256 + n] : c1w[k * 256 + (n - 256)];
            Wt1[(size_t)n * 256 + k] = (f16)v;
        } else {
            int j = i - 512 * 256;
            if (j < 128 * 256) {
                int n = j >> 8, k = j & 255;
                Wt2[(size_t)n * 256 + k] = (f16)c2w[k * 128 + n];
            }
        }
    }
}

// CSR slice allocation without a global scan: wave-prefix + one atomic per wave.
// Row starts are NOT monotone in node id — harmless, each node owns [start, start+cnt).
__global__ __launch_bounds__(256) void k_alloc(const int* __restrict__ counts,
                                               const int* __restrict__ deg,
                                               int* __restrict__ rowstart,
                                               float* __restrict__ dinv,
                                               int* __restrict__ ctr, int nN) {
    int i = blockIdx.x * 256 + threadIdx.x;
    int lane = threadIdx.x & 63;
    int c = (i < nN) ? counts[i] : 0;
    int p = c;
    #pragma unroll
    for (int off = 1; off < 64; off <<= 1) {
        int v = __shfl_up(p, off, 64);
        if (lane >= off) p += v;
    }
    int tot = __shfl(p, 63, 64);
    int base = 0;
    if (lane == 0) base = atomicAdd(ctr, tot);
    base = __shfl(base, 0, 64);
    if (i < nN) {
        rowstart[i] = base + p - c;
        dinv[i] = rsqrtf((float)deg[i]);  // deg >= 1 (self loop)
    }
}

// fill: only src index (u16), no norm materialization (recomputed from dinv in agg)
__global__ void k_fill(const int* __restrict__ ei, int nE, int nN,
                       const int* __restrict__ rowstart,
                       int* __restrict__ fillc, u16* __restrict__ src_sorted) {
    int e = blockIdx.x * blockDim.x + threadIdx.x;
    int total = nE + nN;
    if (e >= total) return;
    int s, d;
    if (e < nE) { s = ei[e]; d = ei[nE + e]; } else { s = d = e - nE; }
    int pos = rowstart[d] + atomicAdd(&fillc[d], 1);
    src_sorted[pos] = (u16)s;
}

// ---------------- AX = A * xh  (gather aggregation, wave per node) ----------------
// half-wave per edge: lane = h*32 + sub; sub covers channels sub*8..sub*8+7 (f16x8 = 16B)
// unrolled x2: 4 gathers in flight per wave; norm = dinv[src]*dinv[node]

__global__ __launch_bounds__(256) void k_aggX(const f16* __restrict__ xh,
                                              const int* __restrict__ rowstart,
                                              const int* __restrict__ counts,
                                              const u16* __restrict__ srcs,
                                              const float* __restrict__ dinv,
                                              f16* __restrict__ AX, int nN) {
    int wv = threadIdx.x >> 6;
    int lane = threadIdx.x & 63;
    int node = blockIdx.x * 4 + wv;
    if (node >= nN) return;
    int h = lane >> 5, sub = lane & 31;
    int beg = rowstart[node];
    int end = beg + counts[node];
    float dn = dinv[node];
    float acc0[8] = {}, acc1[8] = {};
    for (int e0 = beg; e0 < end; e0 += 4) {
        int ea = e0 + h, eb = e0 + 2 + h;
        bool oka = ea < end, okb = eb < end;
        int ia = oka ? ea : beg;
        int ib = okb ? eb : beg;
        int sa = srcs[ia], sb = srcs[ib];
        float na = oka ? dinv[sa] * dn : 0.f;
        float nb = okb ? dinv[sb] * dn : 0.f;
        f16x8 va = *(const f16x8*)(xh + (size_t)sa * 256 + sub * 8);
        f16x8 vb = *(const f16x8*)(xh + (size_t)sb * 256 + sub * 8);
        #pragma unroll
        for (int j = 0; j < 8; j++) {
            acc0[j] = fmaf(na, (float)va[j], acc0[j]);
            acc1[j] = fmaf(nb, (float)vb[j], acc1[j]);
        }
    }
    #pragma unroll
    for (int j = 0; j < 8; j++) {
        acc0[j] += acc1[j];
        acc0[j] += __shfl_xor(acc0[j], 32, 64);
    }
    if (lane < 32) {
        f16x8 o;
        #pragma unroll
        for (int j = 0; j < 8; j++) o[j] = (f16)acc0[j];
        *(f16x8*)(AX + (size_t)node * 256 + sub * 8) = o;
    }
}

// ---------------- GEMM(sig): relu(AX @ sig_w + sigb) column-summed -> sig_part ----------------

__global__ __launch_bounds__(256) void k_gemm_sig(const f16* __restrict__ AX,
                                                  const f16* __restrict__ Wt,
                                                  const float* __restrict__ sigb,
                                                  float* __restrict__ sig_part, int M) {
    __shared__ float tile[32][257];
    int t = threadIdx.x;
    int w = t >> 6, lane = t & 63, quad = lane >> 4, l16 = lane & 15;
    int m0 = blockIdx.x * 32;
    int cb = w * 64;
    f32x4 acc[2][4] = {};
    for (int kk = 0; kk < 256; kk += 32) {
        int ka = kk + quad * 8;
        f16x8 a[2];
        #pragma unroll
        for (int ms = 0; ms < 2; ms++) {
            int row = m0 + ms * 16 + l16; if (row >= M) row = M - 1;
            a[ms] = *(const f16x8*)(AX + (size_t)row * 256 + ka);
        }
        #pragma unroll
        for (int ns = 0; ns < 4; ns++) {
            f16x8 b = *(const f16x8*)(Wt + (size_t)(cb + ns * 16 + l16) * 256 + ka);
            acc[0][ns] = __builtin_amdgcn_mfma_f32_16x16x32_f16(a[0], b, acc[0][ns], 0, 0, 0);
            acc[1][ns] = __builtin_amdgcn_mfma_f32_16x16x32_f16(a[1], b, acc[1][ns], 0, 0, 0);
        }
    }
    #pragma unroll
    for (int ms = 0; ms < 2; ms++)
        #pragma unroll
        for (int ns = 0; ns < 4; ns++)
            #pragma unroll
            for (int r = 0; r < 4; r++) {
                int mr = ms * 16 + quad * 4 + r;
                int c = cb + ns * 16 + l16;
                float v = fmaxf(acc[ms][ns][r] + sigb[c], 0.f);
                if (m0 + mr >= M) v = 0.f;
                tile[mr][c] = v;
            }
    __syncthreads();
    float s = 0.f;
    #pragma unroll 8
    for (int r = 0; r < 32; r++) s += tile[r][t];
    atomicAdd(&sig_part[(blockIdx.x & (NSLOT - 1)) * 256 + t], s);
}

// ---------------- FC: reduce slots -> s, then gamma/beta = tanh(s @ W.T + b) ----------------

__global__ __launch_bounds__(256) void k_fc(const float* __restrict__ sig_part,
                                            const float* __restrict__ f1w, const float* __restrict__ f1b,
                                            const float* __restrict__ f2w, const float* __restrict__ f2b,
                                            const float* __restrict__ f3w, const float* __restrict__ f3b,
                                            const float* __restrict__ f4w, const float* __restrict__ f4b,
                                            float* __restrict__ g1, float* __restrict__ b1,
                                            float* __restrict__ g2, float* __restrict__ b2) {
    __shared__ float ss[256];
    int t = threadIdx.x;
    float s = 0.f;
    for (int k = 0; k < NSLOT; k++) s += sig_part[k * 256 + t];
    ss[t] = s;
    __syncthreads();
    float a1 = 0.f, a2 = 0.f, a3 = 0.f, a4 = 0.f;
    const float* w1 = f1w + (size_t)t * 256;
    const float* w2 = f2w + (size_t)t * 256;
    const float* w3 = f3w + (size_t)(t & 127) * 256;
    const float* w4 = f4w + (size_t)(t & 127) * 256;
    for (int j = 0; j < 256; j++) {
        float sj = ss[j];
        a1 = fmaf(w1[j], sj, a1); a2 = fmaf(w2[j], sj, a2);
        a3 = fmaf(w3[j], sj, a3); a4 = fmaf(w4[j], sj, a4);
    }
    g1[t] = tanhf(a1 + f1b[t]);
    b1[t] = tanhf(a2 + f2b[t]);
    if (t < 128) {
        g2[t] = tanhf(a3 + f3b[t]);
        b2[t] = tanhf(a4 + f4b[t]);
    }
}

// ---------------- fused: conv1-GEMM + FiLM + relu + LN -> (LDS f16 tile) -> conv2-GEMM -> HW ----------------
// block = 32 rows; stage1: 256 cols; stage2: 128 cols. H never hits HBM.

__global__ __launch_bounds__(256) void k_c1f(const f16* __restrict__ AX,
                                             const f16* __restrict__ Wt,   // conv1 rows (256x256)
                                             const f16* __restrict__ Wt2,  // conv2 rows (128x256)
                                             const float* __restrict__ g1,
                                             const float* __restrict__ b1,
                                             const float* __restrict__ c1b,
                                             f16* __restrict__ HW, int M) {
    __shared__ float tile[32][257];
    __shared__ f16 ht[32][264];
    __shared__ float ps[8][33], ps2[8][33];
    __shared__ float mu_[32], rr_[32];
    int t = threadIdx.x;
    int w = t >> 6, lane = t & 63, quad = lane >> 4, l16 = lane & 15;
    int m0 = blockIdx.x * 32;
    int cb = w * 64;
    f32x4 acc[2][4] = {};
    for (int kk = 0; kk < 256; kk += 32) {
        int ka = kk + quad * 8;
        f16x8 a[2];
        #pragma unroll
        for (int ms = 0; ms < 2; ms++) {
            int row = m0 + ms * 16 + l16; if (row >= M) row = M - 1;
            a[ms] = *(const f16x8*)(AX + (size_t)row * 256 + ka);
        }
        #pragma unroll
        for (int ns = 0; ns < 4; ns++) {
            f16x8 b = *(const f16x8*)(Wt + (size_t)(cb + ns * 16 + l16) * 256 + ka);
            acc[0][ns] = __builtin_amdgcn_mfma_f32_16x16x32_f16(a[0], b, acc[0][ns], 0, 0, 0);
            acc[1][ns] = __builtin_amdgcn_mfma_f32_16x16x32_f16(a[1], b, acc[1][ns], 0, 0, 0);
        }
    }
    #pragma unroll
    for (int ms = 0; ms < 2; ms++)
        #pragma unroll
        for (int ns = 0; ns < 4; ns++)
            #pragma unroll
            for (int r = 0; r < 4; r++) {
                int mr = ms * 16 + quad * 4 + r;
                int c = cb + ns * 16 + l16;
                tile[mr][c] = fmaxf(fmaf(g1[c], acc[ms][ns][r], b1[c] + c1b[c]), 0.f);
            }
    __syncthreads();
    // LN stats: r = t&31, seg = t>>5 covers 32 cols
    {
        int r = t & 31, seg = t >> 5;
        float s = 0.f, s2 = 0.f;
        #pragma unroll 8
        for (int c = seg * 32; c < seg * 32 + 32; c++) {
            float xv = tile[r][c];
            s += xv; s2 = fmaf(xv, xv, s2);
        }
        ps[seg][r] = s; ps2[seg][r] = s2;
    }
    __syncthreads();
    if (t < 32) {
        float S = 0.f, S2 = 0.f;
        #pragma unroll
        for (int g = 0; g < 8; g++) { S += ps[g][t]; S2 += ps2[g][t]; }
        float mu = S * (1.f / 256.f);
        mu_[t] = mu;
        rr_[t] = rsqrtf(S2 * (1.f / 256.f) - mu * mu + LN_EPS);
    }
    __syncthreads();
    #pragma unroll 8
    for (int r = 0; r < 32; r++)
        ht[r][t] = (f16)((tile[r][t] - mu_[r]) * rr_[r]);
    __syncthreads();
    // stage 2: HW[32 x 128] = ht @ Wt2^T
    int cb2 = w * 32;
    f32x4 acc2[2][2] = {};
    for (int kk = 0; kk < 256; kk += 32) {
        int ka = kk + quad * 8;
        f16x8 a[2];
        #pragma unroll
        for (int ms = 0; ms < 2; ms++)
            a[ms] = *(const f16x8*)(&ht[ms * 16 + l16][ka]);
        #pragma unroll
        for (int ns = 0; ns < 2; ns++) {
            f16x8 b = *(const f16x8*)(Wt2 + (size_t)(cb2 + ns * 16 + l16) * 256 + ka);
            acc2[0][ns] = __builtin_amdgcn_mfma_f32_16x16x32_f16(a[0], b, acc2[0][ns], 0, 0, 0);
            acc2[1][ns] = __builtin_amdgcn_mfma_f32_16x16x32_f16(a[1], b, acc2[1][ns], 0, 0, 0);
        }
    }
    #pragma unroll
    for (int ms = 0; ms < 2; ms++)
        #pragma unroll
        for (int ns = 0; ns < 2; ns++)
            #pragma unroll
            for (int r = 0; r < 4; r++) {
                int m = m0 + ms * 16 + quad * 4 + r;
                if (m < M) HW[(size_t)m * 128 + cb2 + ns * 16 + l16] = (f16)acc2[ms][ns][r];
            }
}

// ---------------- agg2: out = LN(g2 * (A*HW) + b2 + c2b)  (wave per node) ----------------
// quarter-wave per edge; unrolled x2: 8 gathers in flight; norm from dinv

__global__ __launch_bounds__(256) void k_agg2(const f16* __restrict__ HW,
                                              const int* __restrict__ rowstart,
                                              const int* __restrict__ counts,
                                              const u16* __restrict__ srcs,
                                              const float* __restrict__ dinv,
                                              const float* __restrict__ g2,
                                              const float* __restrict__ b2,
                                              const float* __restrict__ c2b,
                                              float* __restrict__ out, int nN) {
    int wv = threadIdx.x >> 6;
    int lane = threadIdx.x & 63;
    int node = blockIdx.x * 4 + wv;
    if (node >= nN) return;
    int q = lane >> 4, sub = lane & 15;
    int beg = rowstart[node];
    int end = beg + counts[node];
    float dn = dinv[node];
    float acc0[8] = {}, acc1[8] = {};
    for (int e0 = beg; e0 < end; e0 += 8) {
        int ea = e0 + q, eb = e0 + 4 + q;
        bool oka = ea < end, okb = eb < end;
        int ia = oka ? ea : beg;
        int ib = okb ? eb : beg;
        int sa = srcs[ia], sb = srcs[ib];
        float na = oka ? dinv[sa] * dn : 0.f;
        float nb = okb ? dinv[sb] * dn : 0.f;
        f16x8 va = *(const f16x8*)(HW + (size_t)sa * 128 + sub * 8);
        f16x8 vb = *(const f16x8*)(HW + (size_t)sb * 128 + sub * 8);
        #pragma unroll
        for (int j = 0; j < 8; j++) {
            acc0[j] = fmaf(na, (float)va[j], acc0[j]);
            acc1[j] = fmaf(nb, (float)vb[j], acc1[j]);
        }
    }
    #pragma unroll
    for (int j = 0; j < 8; j++) {
        acc0[j] += acc1[j];
        acc0[j] += __shfl_xor(acc0[j], 16, 64);
        acc0[j] += __shfl_xor(acc0[j], 32, 64);
    }
    int ch = sub * 8;
    float vfin[8];
    float s = 0.f, s2 = 0.f;
    #pragma unroll
    for (int j = 0; j < 8; j++) {
        float v = fmaf(g2[ch + j], acc0[j], b2[ch + j] + c2b[ch + j]);
        vfin[j] = v;
        s += v; s2 = fmaf(v, v, s2);
    }
    #pragma unroll
    for (int off = 1; off < 16; off <<= 1) {
        s += __shfl_xor(s, off, 64);
        s2 += __shfl_xor(s2, off, 64);
    }
    float mu = s * (1.f / 128.f);
    float rr = rsqrtf(s2 * (1.f / 128.f) - mu * mu + LN_EPS);
    if (q == 0) {
        float4 o0 = { (vfin[0] - mu) * rr, (vfin[1] - mu) * rr,
                      (vfin[2] - mu) * rr, (vfin[3] - mu) * rr };
        float4 o1 = { (vfin[4] - mu) * rr, (vfin[5] - mu) * rr,
                      (vfin[6] - mu) * rr, (vfin[7] - mu) * rr };
        float* dst = out + (size_t)node * 128 + ch;
        *(float4*)dst = o0;
        *(float4*)(dst + 4) = o1;
    }
}

// ---------------- host launch ----------------

extern "C" void kernel_launch(void* const* d_in, const int* in_sizes, int n_in,
                              void* d_out, int out_size, void* d_ws, size_t ws_size,
                              hipStream_t stream) {
    const float* x    = (const float*)d_in[0];
    const int*   ei   = (const int*)d_in[1];
    const float* c1w  = (const float*)d_in[2];
    const float* c1b  = (const float*)d_in[3];
    const float* c2w  = (const float*)d_in[4];
    const float* c2b  = (const float*)d_in[5];
    const float* sigw = (const float*)d_in[6];
    const float* sigb = (const float*)d_in[7];
    const float* f1w  = (const float*)d_in[8];
    const float* f1b  = (const float*)d_in[9];
    const float* f2w  = (const float*)d_in[10];
    const float* f2b  = (const float*)d_in[11];
    const float* f3w  = (const float*)d_in[12];
    const float* f3b  = (const float*)d_in[13];
    const float* f4w  = (const float*)d_in[14];
    const float* f4b  = (const float*)d_in[15];
    float* out = (float*)d_out;

    int nN = in_sizes[0] / IN_CH;      // 50000
    int nE = in_sizes[1] / 2;          // 800000
    int nT = nE + nN;                  // 850000

    char* base = (char*)d_ws;
    size_t off = 0;
    auto alloc = [&](size_t bytes) { size_t o = off; off += (bytes + 255) & ~(size_t)255; return o; };

    size_t o_deg    = alloc((size_t)nN * 4);
    size_t o_counts = alloc((size_t)nN * 4);
    size_t o_fillc  = alloc((size_t)nN * 4);
    size_t o_spart  = alloc((size_t)NSLOT * 256 * 4);
    size_t o_ctr    = alloc(256);
    size_t zero_bytes = off;                   // zero deg/counts/fillc/sig_part/ctr
    size_t o_g1     = alloc(256 * 4);
    size_t o_b1     = alloc(256 * 4);
    size_t o_g2     = alloc(128 * 4);
    size_t o_b2     = alloc(128 * 4);
    size_t o_rowst  = alloc((size_t)nN * 4);
    size_t o_dinv   = alloc((size_t)nN * 4);
    size_t o_src    = alloc((size_t)nT * 2);
    size_t o_wt1    = alloc(512 * 256 * 2);
    size_t o_wt2    = alloc(128 * 256 * 2);
    size_t o_xh     = alloc((size_t)nN * 256 * 2);
    size_t o_AX     = alloc((size_t)nN * 256 * 2);
    size_t o_HW     = alloc((size_t)nN * 128 * 2);

    int*   deg    = (int*)(base + o_deg);
    int*   counts = (int*)(base + o_counts);
    int*   fillc  = (int*)(base + o_fillc);
    float* spart  = (float*)(base + o_spart);
    int*   ctr    = (int*)(base + o_ctr);
    float* g1     = (float*)(base + o_g1);
    float* b1     = (float*)(base + o_b1);
    float* g2     = (float*)(base + o_g2);
    float* b2     = (float*)(base + o_b2);
    int*   rowst  = (int*)(base + o_rowst);
    float* dinv   = (float*)(base + o_dinv);
    u16*   srcs   = (u16*)(base + o_src);
    f16*   Wt1    = (f16*)(base + o_wt1);
    f16*   Wt2    = (f16*)(base + o_wt2);
    f16*   xh     = (f16*)(base + o_xh);
    f16*   AX     = (f16*)(base + o_AX);
    f16*   HW     = (f16*)(base + o_HW);

    hipMemsetAsync(base, 0, zero_bytes, stream);

    int nCast = (nN * IN_CH / 8 + 255) / 256;          // 6250
    int nHist = (nT + 255) / 256;                      // 3321
    int nPrep = (512 * 256 + 128 * 256) / 256;         // 640
    int nOdd  = nHist + nPrep;
    int gPre  = 2 * (nCast > nOdd ? nCast : nOdd);
    k_pre0<<<gPre, 256, 0, stream>>>(x, xh, nN * IN_CH, ei, nE, nN, deg, counts,
                                     sigw, c1w, c2w, Wt1, Wt2, nCast, nHist);
    k_alloc<<<(nN + 255) / 256, 256, 0, stream>>>(counts, deg, rowst, dinv, ctr, nN);
    k_fill<<<(nT + 255) / 256, 256, 0, stream>>>(ei, nE, nN, rowst, fillc, srcs);

    int nb4 = (nN + 3) / 4;
    int mg = (nN + 31) / 32;
    k_aggX<<<nb4, 256, 0, stream>>>(xh, rowst, counts, srcs, dinv, AX, nN);
    k_gemm_sig<<<mg, 256, 0, stream>>>(AX, Wt1, sigb, spart, nN);
    k_fc<<<1, 256, 0, stream>>>(spart, f1w, f1b, f2w, f2b, f3w, f3b, f4w, f4b, g1, b1, g2, b2);
    k_c1f<<<mg, 256, 0, stream>>>(AX, Wt1 + 256 * 256, Wt2, g1, b1, c1b, HW, nN);
    k_agg2<<<nb4, 256, 0, stream>>>(HW, rowst, counts, srcs, dinv, g2, b2, c2b, out, nN);
}

// Round 5
// 469.199 us; speedup vs baseline: 1.5859x; 1.0205x over previous
//
#include <hip/hip_runtime.h>

typedef _Float16 f16;
typedef f16 f16x8 __attribute__((ext_vector_type(8)));
typedef float f32x4 __attribute__((ext_vector_type(4)));
typedef unsigned short u16;

#define IN_CH  256
#define HID    256
#define OUT_CH 128
#define LN_EPS 1e-5f
#define NSLOT  32   // sig partial slots (atomic contention spreading)

// ---------------- fused pre-pass: cast | 8-copy edge histogram | weight prep ----------------
// bid layout: groups of 16; low 3 bits preserved so hist chunk h runs on bid%8 == h&7
// (XCD-local under round-robin dispatch; copy index = h&7 in BOTH hist and fill)

__global__ __launch_bounds__(256) void k_pre0(const float* __restrict__ x, f16* __restrict__ xh, int nelem,
                                              const int* __restrict__ ei, int nE, int nN,
                                              int* __restrict__ deg8, int* __restrict__ counts8,
                                              const float* __restrict__ sigw, const float* __restrict__ c1w,
                                              const float* __restrict__ c2w,
                                              f16* __restrict__ Wt1, f16* __restrict__ Wt2,
                                              int nCast, int nHist, int nOdd) {
    int bid = blockIdx.x;
    int group = bid >> 4, lane3 = bid & 7, sel = (bid >> 3) & 1;
    int chunk = group * 8 + lane3;
    if (sel == 0) {
        if (chunk >= nCast) return;
        int i = chunk * 2048 + threadIdx.x * 8;
        if (i >= nelem) return;
        float4 a = *(const float4*)(x + i);
        float4 b = *(const float4*)(x + i + 4);
        f16x8 o = { (f16)a.x, (f16)a.y, (f16)a.z, (f16)a.w,
                    (f16)b.x, (f16)b.y, (f16)b.z, (f16)b.w };
        *(f16x8*)(xh + i) = o;
    } else {
        if (chunk >= nOdd) return;
        if (chunk < nHist) {
            int e = chunk * 256 + threadIdx.x;
            int total = nE + nN;
            if (e >= total) return;
            int s, d;
            if (e < nE) { s = ei[e]; d = ei[nE + e]; } else { s = d = e - nE; }
            atomicAdd(&deg8[lane3 * nN + s], 1);
            atomicAdd(&counts8[lane3 * nN + d], 1);
        } else {
            int i = (chunk - nHist) * 256 + threadIdx.x;
            if (i < 512 * 256) {
                int n = i >> 8, k = i & 255;
                float v = (n < 256) ? sigw[k * 256 + n] : c1w[k * 256 + (n - 256)];
                Wt1[(size_t)n * 256 + k] = (f16)v;
            } else {
                int j = i - 512 * 256;
                if (j < 128 * 256) {
                    int n = j >> 8, k = j & 255;
                    Wt2[(size_t)n * 256 + k] = (f16)c2w[k * 128 + n];
                }
            }
        }
    }
}

// reduce 8 histogram copies, allocate CSR slices (wave-prefix + 1 atomic/wave),
// lay out per-(node,copy) sub-slices so fill's atomics are copy-local, compute dinv
__global__ __launch_bounds__(256) void k_alloc(const int* __restrict__ counts8,
                                               const int* __restrict__ deg8,
                                               int* __restrict__ rowstart,
                                               int* __restrict__ rowstart8,
                                               int* __restrict__ cnt_tot,
                                               float* __restrict__ dinv,
                                               int* __restrict__ ctr, int nN) {
    int i = blockIdx.x * 256 + threadIdx.x;
    int lane = threadIdx.x & 63;
    int c8[8];
    int cnt = 0, dg = 0;
    if (i < nN) {
        #pragma unroll
        for (int c = 0; c < 8; c++) {
            c8[c] = counts8[(size_t)c * nN + i];
            cnt += c8[c];
            dg += deg8[(size_t)c * nN + i];
        }
    } else {
        #pragma unroll
        for (int c = 0; c < 8; c++) c8[c] = 0;
    }
    int p = cnt;
    #pragma unroll
    for (int off = 1; off < 64; off <<= 1) {
        int v = __shfl_up(p, off, 64);
        if (lane >= off) p += v;
    }
    int tot = __shfl(p, 63, 64);
    int base = 0;
    if (lane == 0) base = atomicAdd(ctr, tot);
    base = __shfl(base, 0, 64);
    if (i < nN) {
        int nb = base + p - cnt;
        rowstart[i] = nb;
        cnt_tot[i] = cnt;
        int run = nb;
        #pragma unroll
        for (int c = 0; c < 8; c++) { rowstart8[(size_t)c * nN + i] = run; run += c8[c]; }
        dinv[i] = rsqrtf((float)dg);  // deg >= 1 (self loop)
    }
}

// fill (copy-local fillc atomics) + fused xh *= dinv[row] scaling pass
__global__ __launch_bounds__(256) void k_fill(const int* __restrict__ ei, int nE, int nN,
                                              const int* __restrict__ rowstart8,
                                              int* __restrict__ fillc8, u16* __restrict__ src_sorted,
                                              f16* __restrict__ xh, const float* __restrict__ dinv,
                                              int nFill, int nScale) {
    int bid = blockIdx.x;
    if (bid < nFill) {
        int e = bid * 256 + threadIdx.x;
        int total = nE + nN;
        if (e >= total) return;
        int s, d;
        if (e < nE) { s = ei[e]; d = ei[nE + e]; } else { s = d = e - nE; }
        int c = bid & 7;
        int pos = rowstart8[(size_t)c * nN + d] + atomicAdd(&fillc8[(size_t)c * nN + d], 1);
        src_sorted[pos] = (u16)s;
    } else {
        int sb = bid - nFill;
        if (sb >= nScale) return;
        int i = sb * 2048 + threadIdx.x * 8;
        if (i >= nN * 256) return;
        float dn = dinv[i >> 8];
        f16x8 v = *(const f16x8*)(xh + i);
        #pragma unroll
        for (int j = 0; j < 8; j++) v[j] = (f16)((float)v[j] * dn);
        *(f16x8*)(xh + i) = v;
    }
}

// ---------------- AX = dinv_d * sum(xh'[src])  (xh pre-scaled by dinv_src) ----------------
// wave per node; half-wave per edge; 16B loads; x2 unroll = 4 gathers in flight

__global__ __launch_bounds__(256) void k_aggX(const f16* __restrict__ xh,
                                              const int* __restrict__ rowstart,
                                              const int* __restrict__ counts,
                                              const u16* __restrict__ srcs,
                                              const float* __restrict__ dinv,
                                              f16* __restrict__ AX, int nN) {
    int wv = threadIdx.x >> 6;
    int lane = threadIdx.x & 63;
    int node = blockIdx.x * 4 + wv;
    if (node >= nN) return;
    int h = lane >> 5, sub = lane & 31;
    int beg = rowstart[node];
    int end = beg + counts[node];
    float acc0[8] = {}, acc1[8] = {};
    for (int e0 = beg; e0 < end; e0 += 4) {
        int ea = e0 + h, eb = e0 + 2 + h;
        bool oka = ea < end, okb = eb < end;
        int ia = oka ? ea : beg;
        int ib = okb ? eb : beg;
        int sa = srcs[ia], sb = srcs[ib];
        float na = oka ? 1.f : 0.f;
        float nb = okb ? 1.f : 0.f;
        f16x8 va = *(const f16x8*)(xh + (size_t)sa * 256 + sub * 8);
        f16x8 vb = *(const f16x8*)(xh + (size_t)sb * 256 + sub * 8);
        #pragma unroll
        for (int j = 0; j < 8; j++) {
            acc0[j] = fmaf(na, (float)va[j], acc0[j]);
            acc1[j] = fmaf(nb, (float)vb[j], acc1[j]);
        }
    }
    float dn = dinv[node];
    #pragma unroll
    for (int j = 0; j < 8; j++) {
        acc0[j] += acc1[j];
        acc0[j] += __shfl_xor(acc0[j], 32, 64);
    }
    if (lane < 32) {
        f16x8 o;
        #pragma unroll
        for (int j = 0; j < 8; j++) o[j] = (f16)(acc0[j] * dn);
        *(f16x8*)(AX + (size_t)node * 256 + sub * 8) = o;
    }
}

// ---------------- GEMM(sig): relu(AX @ sig_w + sigb) column-summed -> sig_part ----------------

__global__ __launch_bounds__(256) void k_gemm_sig(const f16* __restrict__ AX,
                                                  const f16* __restrict__ Wt,
                                                  const float* __restrict__ sigb,
                                                  float* __restrict__ sig_part, int M) {
    __shared__ float tile[32][257];
    int t = threadIdx.x;
    int w = t >> 6, lane = t & 63, quad = lane >> 4, l16 = lane & 15;
    int m0 = blockIdx.x * 32;
    int cb = w * 64;
    f32x4 acc[2][4] = {};
    for (int kk = 0; kk < 256; kk += 32) {
        int ka = kk + quad * 8;
        f16x8 a[2];
        #pragma unroll
        for (int ms = 0; ms < 2; ms++) {
            int row = m0 + ms * 16 + l16; if (row >= M) row = M - 1;
            a[ms] = *(const f16x8*)(AX + (size_t)row * 256 + ka);
        }
        #pragma unroll
        for (int ns = 0; ns < 4; ns++) {
            f16x8 b = *(const f16x8*)(Wt + (size_t)(cb + ns * 16 + l16) * 256 + ka);
            acc[0][ns] = __builtin_amdgcn_mfma_f32_16x16x32_f16(a[0], b, acc[0][ns], 0, 0, 0);
            acc[1][ns] = __builtin_amdgcn_mfma_f32_16x16x32_f16(a[1], b, acc[1][ns], 0, 0, 0);
        }
    }
    #pragma unroll
    for (int ms = 0; ms < 2; ms++)
        #pragma unroll
        for (int ns = 0; ns < 4; ns++)
            #pragma unroll
            for (int r = 0; r < 4; r++) {
                int mr = ms * 16 + quad * 4 + r;
                int c = cb + ns * 16 + l16;
                float v = fmaxf(acc[ms][ns][r] + sigb[c], 0.f);
                if (m0 + mr >= M) v = 0.f;
                tile[mr][c] = v;
            }
    __syncthreads();
    float s = 0.f;
    #pragma unroll 8
    for (int r = 0; r < 32; r++) s += tile[r][t];
    atomicAdd(&sig_part[(blockIdx.x & (NSLOT - 1)) * 256 + t], s);
}

// ---------------- FC: reduce slots -> s, then gamma/beta = tanh(s @ W.T + b) ----------------

__global__ __launch_bounds__(256) void k_fc(const float* __restrict__ sig_part,
                                            const float* __restrict__ f1w, const float* __restrict__ f1b,
                                            const float* __restrict__ f2w, const float* __restrict__ f2b,
                                            const float* __restrict__ f3w, const float* __restrict__ f3b,
                                            const float* __restrict__ f4w, const float* __restrict__ f4b,
                                            float* __restrict__ g1, float* __restrict__ b1,
                                            float* __restrict__ g2, float* __restrict__ b2) {
    __shared__ float ss[256];
    int t = threadIdx.x;
    float s = 0.f;
    for (int k = 0; k < NSLOT; k++) s += sig_part[k * 256 + t];
    ss[t] = s;
    __syncthreads();
    float a1 = 0.f, a2 = 0.f, a3 = 0.f, a4 = 0.f;
    const float* w1 = f1w + (size_t)t * 256;
    const float* w2 = f2w + (size_t)t * 256;
    const float* w3 = f3w + (size_t)(t & 127) * 256;
    const float* w4 = f4w + (size_t)(t & 127) * 256;
    for (int j = 0; j < 256; j++) {
        float sj = ss[j];
        a1 = fmaf(w1[j], sj, a1); a2 = fmaf(w2[j], sj, a2);
        a3 = fmaf(w3[j], sj, a3); a4 = fmaf(w4[j], sj, a4);
    }
    g1[t] = tanhf(a1 + f1b[t]);
    b1[t] = tanhf(a2 + f2b[t]);
    if (t < 128) {
        g2[t] = tanhf(a3 + f3b[t]);
        b2[t] = tanhf(a4 + f4b[t]);
    }
}

// ---------------- fused: conv1-GEMM + FiLM + relu + LN -> (LDS) -> conv2-GEMM -> HW' ----------------
// HW' rows pre-scaled by dinv[m] so agg2 needs no per-edge dinv gather

__global__ __launch_bounds__(256) void k_c1f(const f16* __restrict__ AX,
                                             const f16* __restrict__ Wt,   // conv1 rows (256x256)
                                             const f16* __restrict__ Wt2,  // conv2 rows (128x256)
                                             const float* __restrict__ g1,
                                             const float* __restrict__ b1,
                                             const float* __restrict__ c1b,
                                             const float* __restrict__ dinv,
                                             f16* __restrict__ HW, int M) {
    __shared__ float tile[32][257];
    __shared__ f16 ht[32][264];
    __shared__ float ps[8][33], ps2[8][33];
    __shared__ float mu_[32], rr_[32], sdinv[32];
    int t = threadIdx.x;
    int w = t >> 6, lane = t & 63, quad = lane >> 4, l16 = lane & 15;
    int m0 = blockIdx.x * 32;
    int cb = w * 64;
    f32x4 acc[2][4] = {};
    for (int kk = 0; kk < 256; kk += 32) {
        int ka = kk + quad * 8;
        f16x8 a[2];
        #pragma unroll
        for (int ms = 0; ms < 2; ms++) {
            int row = m0 + ms * 16 + l16; if (row >= M) row = M - 1;
            a[ms] = *(const f16x8*)(AX + (size_t)row * 256 + ka);
        }
        #pragma unroll
        for (int ns = 0; ns < 4; ns++) {
            f16x8 b = *(const f16x8*)(Wt + (size_t)(cb + ns * 16 + l16) * 256 + ka);
            acc[0][ns] = __builtin_amdgcn_mfma_f32_16x16x32_f16(a[0], b, acc[0][ns], 0, 0, 0);
            acc[1][ns] = __builtin_amdgcn_mfma_f32_16x16x32_f16(a[1], b, acc[1][ns], 0, 0, 0);
        }
    }
    #pragma unroll
    for (int ms = 0; ms < 2; ms++)
        #pragma unroll
        for (int ns = 0; ns < 4; ns++)
            #pragma unroll
            for (int r = 0; r < 4; r++) {
                int mr = ms * 16 + quad * 4 + r;
                int c = cb + ns * 16 + l16;
                tile[mr][c] = fmaxf(fmaf(g1[c], acc[ms][ns][r], b1[c] + c1b[c]), 0.f);
            }
    __syncthreads();
    {
        int r = t & 31, seg = t >> 5;
        float s = 0.f, s2 = 0.f;
        #pragma unroll 8
        for (int c = seg * 32; c < seg * 32 + 32; c++) {
            float xv = tile[r][c];
            s += xv; s2 = fmaf(xv, xv, s2);
        }
        ps[seg][r] = s; ps2[seg][r] = s2;
    }
    __syncthreads();
    if (t < 32) {
        float S = 0.f, S2 = 0.f;
        #pragma unroll
        for (int g = 0; g < 8; g++) { S += ps[g][t]; S2 += ps2[g][t]; }
        float mu = S * (1.f / 256.f);
        mu_[t] = mu;
        rr_[t] = rsqrtf(S2 * (1.f / 256.f) - mu * mu + LN_EPS);
        int m = m0 + t;
        sdinv[t] = (m < M) ? dinv[m] : 0.f;
    }
    __syncthreads();
    #pragma unroll 8
    for (int r = 0; r < 32; r++)
        ht[r][t] = (f16)((tile[r][t] - mu_[r]) * rr_[r]);
    __syncthreads();
    // stage 2: HW'[32 x 128] = dinv_row * (ht @ Wt2^T)
    int cb2 = w * 32;
    f32x4 acc2[2][2] = {};
    for (int kk = 0; kk < 256; kk += 32) {
        int ka = kk + quad * 8;
        f16x8 a[2];
        #pragma unroll
        for (int ms = 0; ms < 2; ms++)
            a[ms] = *(const f16x8*)(&ht[ms * 16 + l16][ka]);
        #pragma unroll
        for (int ns = 0; ns < 2; ns++) {
            f16x8 b = *(const f16x8*)(Wt2 + (size_t)(cb2 + ns * 16 + l16) * 256 + ka);
            acc2[0][ns] = __builtin_amdgcn_mfma_f32_16x16x32_f16(a[0], b, acc2[0][ns], 0, 0, 0);
            acc2[1][ns] = __builtin_amdgcn_mfma_f32_16x16x32_f16(a[1], b, acc2[1][ns], 0, 0, 0);
        }
    }
    #pragma unroll
    for (int ms = 0; ms < 2; ms++)
        #pragma unroll
        for (int ns = 0; ns < 2; ns++)
            #pragma unroll
            for (int r = 0; r < 4; r++) {
                int mr = ms * 16 + quad * 4 + r;
                int m = m0 + mr;
                if (m < M) HW[(size_t)m * 128 + cb2 + ns * 16 + l16] = (f16)(acc2[ms][ns][r] * sdinv[mr]);
            }
}

// ---------------- agg2: out = LN(g2 * dinv_d * sum(HW'[src]) + b2 + c2b) ----------------
// wave per node; quarter-wave per edge; x2 unroll = 8 gathers in flight

__global__ __launch_bounds__(256) void k_agg2(const f16* __restrict__ HW,
                                              const int* __restrict__ rowstart,
                                              const int* __restrict__ counts,
                                              const u16* __restrict__ srcs,
                                              const float* __restrict__ dinv,
                                              const float* __restrict__ g2,
                                              const float* __restrict__ b2,
                                              const float* __restrict__ c2b,
                                              float* __restrict__ out, int nN) {
    int wv = threadIdx.x >> 6;
    int lane = threadIdx.x & 63;
    int node = blockIdx.x * 4 + wv;
    if (node >= nN) return;
    int q = lane >> 4, sub = lane & 15;
    int beg = rowstart[node];
    int end = beg + counts[node];
    float acc0[8] = {}, acc1[8] = {};
    for (int e0 = beg; e0 < end; e0 += 8) {
        int ea = e0 + q, eb = e0 + 4 + q;
        bool oka = ea < end, okb = eb < end;
        int ia = oka ? ea : beg;
        int ib = okb ? eb : beg;
        int sa = srcs[ia], sb = srcs[ib];
        float na = oka ? 1.f : 0.f;
        float nb = okb ? 1.f : 0.f;
        f16x8 va = *(const f16x8*)(HW + (size_t)sa * 128 + sub * 8);
        f16x8 vb = *(const f16x8*)(HW + (size_t)sb * 128 + sub * 8);
        #pragma unroll
        for (int j = 0; j < 8; j++) {
            acc0[j] = fmaf(na, (float)va[j], acc0[j]);
            acc1[j] = fmaf(nb, (float)vb[j], acc1[j]);
        }
    }
    float dn = dinv[node];
    #pragma unroll
    for (int j = 0; j < 8; j++) {
        acc0[j] += acc1[j];
        acc0[j] += __shfl_xor(acc0[j], 16, 64);
        acc0[j] += __shfl_xor(acc0[j], 32, 64);
    }
    int ch = sub * 8;
    float vfin[8];
    float s = 0.f, s2 = 0.f;
    #pragma unroll
    for (int j = 0; j < 8; j++) {
        float v = fmaf(g2[ch + j], acc0[j] * dn, b2[ch + j] + c2b[ch + j]);
        vfin[j] = v;
        s += v; s2 = fmaf(v, v, s2);
    }
    #pragma unroll
    for (int off = 1; off < 16; off <<= 1) {
        s += __shfl_xor(s, off, 64);
        s2 += __shfl_xor(s2, off, 64);
    }
    float mu = s * (1.f / 128.f);
    float rr = rsqrtf(s2 * (1.f / 128.f) - mu * mu + LN_EPS);
    if (q == 0) {
        float4 o0 = { (vfin[0] - mu) * rr, (vfin[1] - mu) * rr,
                      (vfin[2] - mu) * rr, (vfin[3] - mu) * rr };
        float4 o1 = { (vfin[4] - mu) * rr, (vfin[5] - mu) * rr,
                      (vfin[6] - mu) * rr, (vfin[7] - mu) * rr };
        float* dst = out + (size_t)node * 128 + ch;
        *(float4*)dst = o0;
        *(float4*)(dst + 4) = o1;
    }
}

// ---------------- host launch ----------------

extern "C" void kernel_launch(void* const* d_in, const int* in_sizes, int n_in,
                              void* d_out, int out_size, void* d_ws, size_t ws_size,
                              hipStream_t stream) {
    const float* x    = (const float*)d_in[0];
    const int*   ei   = (const int*)d_in[1];
    const float* c1w  = (const float*)d_in[2];
    const float* c1b  = (const float*)d_in[3];
    const float* c2w  = (const float*)d_in[4];
    const float* c2b  = (const float*)d_in[5];
    const float* sigw = (const float*)d_in[6];
    const float* sigb = (const float*)d_in[7];
    const float* f1w  = (const float*)d_in[8];
    const float* f1b  = (const float*)d_in[9];
    const float* f2w  = (const float*)d_in[10];
    const float* f2b  = (const float*)d_in[11];
    const float* f3w  = (const float*)d_in[12];
    const float* f3b  = (const float*)d_in[13];
    const float* f4w  = (const float*)d_in[14];
    const float* f4b  = (const float*)d_in[15];
    float* out = (float*)d_out;

    int nN = in_sizes[0] / IN_CH;      // 50000
    int nE = in_sizes[1] / 2;          // 800000
    int nT = nE + nN;                  // 850000

    char* base = (char*)d_ws;
    size_t off = 0;
    auto alloc = [&](size_t bytes) { size_t o = off; off += (bytes + 255) & ~(size_t)255; return o; };

    size_t o_deg8   = alloc((size_t)8 * nN * 4);
    size_t o_cnt8   = alloc((size_t)8 * nN * 4);
    size_t o_fillc8 = alloc((size_t)8 * nN * 4);
    size_t o_spart  = alloc((size_t)NSLOT * 256 * 4);
    size_t o_ctr    = alloc(256);
    size_t zero_bytes = off;                   // zero deg8/counts8/fillc8/sig_part/ctr
    size_t o_g1     = alloc(256 * 4);
    size_t o_b1     = alloc(256 * 4);
    size_t o_g2     = alloc(128 * 4);
    size_t o_b2     = alloc(128 * 4);
    size_t o_rowst  = alloc((size_t)nN * 4);
    size_t o_rowst8 = alloc((size_t)8 * nN * 4);
    size_t o_cntt   = alloc((size_t)nN * 4);
    size_t o_dinv   = alloc((size_t)nN * 4);
    size_t o_src    = alloc((size_t)nT * 2);
    size_t o_wt1    = alloc(512 * 256 * 2);
    size_t o_wt2    = alloc(128 * 256 * 2);
    size_t o_xh     = alloc((size_t)nN * 256 * 2);
    size_t o_AX     = alloc((size_t)nN * 256 * 2);
    size_t o_HW     = alloc((size_t)nN * 128 * 2);

    int*   deg8   = (int*)(base + o_deg8);
    int*   cnts8  = (int*)(base + o_cnt8);
    int*   fillc8 = (int*)(base + o_fillc8);
    float* spart  = (float*)(base + o_spart);
    int*   ctr    = (int*)(base + o_ctr);
    float* g1     = (float*)(base + o_g1);
    float* b1     = (float*)(base + o_b1);
    float* g2     = (float*)(base + o_g2);
    float* b2     = (float*)(base + o_b2);
    int*   rowst  = (int*)(base + o_rowst);
    int*   rowst8 = (int*)(base + o_rowst8);
    int*   cntt   = (int*)(base + o_cntt);
    float* dinv   = (float*)(base + o_dinv);
    u16*   srcs   = (u16*)(base + o_src);
    f16*   Wt1    = (f16*)(base + o_wt1);
    f16*   Wt2    = (f16*)(base + o_wt2);
    f16*   xh     = (f16*)(base + o_xh);
    f16*   AX     = (f16*)(base + o_AX);
    f16*   HW     = (f16*)(base + o_HW);

    hipMemsetAsync(base, 0, zero_bytes, stream);

    int nCast = (nN * IN_CH + 2047) / 2048;            // 6250
    int nHist = (nT + 255) / 256;                      // 3321
    int nPrep = (512 * 256 + 128 * 256) / 256;         // 640
    int nOdd  = nHist + nPrep;                         // 3961
    int nMax  = nCast > nOdd ? nCast : nOdd;
    int gPre  = ((nMax + 7) / 8) * 16;
    k_pre0<<<gPre, 256, 0, stream>>>(x, xh, nN * IN_CH, ei, nE, nN, deg8, cnts8,
                                     sigw, c1w, c2w, Wt1, Wt2, nCast, nHist, nOdd);
    k_alloc<<<(nN + 255) / 256, 256, 0, stream>>>(cnts8, deg8, rowst, rowst8, cntt, dinv, ctr, nN);

    int nFill = (nT + 255) / 256;
    int nScale = (nN * IN_CH + 2047) / 2048;
    k_fill<<<nFill + nScale, 256, 0, stream>>>(ei, nE, nN, rowst8, fillc8, srcs,
                                               xh, dinv, nFill, nScale);

    int nb4 = (nN + 3) / 4;
    int mg = (nN + 31) / 32;
    k_aggX<<<nb4, 256, 0, stream>>>(xh, rowst, cntt, srcs, dinv, AX, nN);
    k_gemm_sig<<<mg, 256, 0, stream>>>(AX, Wt1, sigb, spart, nN);
    k_fc<<<1, 256, 0, stream>>>(spart, f1w, f1b, f2w, f2b, f3w, f3b, f4w, f4b, g1, b1, g2, b2);
    k_c1f<<<mg, 256, 0, stream>>>(AX, Wt1 + 256 * 256, Wt2, g1, b1, c1b, dinv, HW, nN);
    k_agg2<<<nb4, 256, 0, stream>>>(HW, rowst, cntt, srcs, dinv, g2, b2, c2b, out, nN);
}

// Round 6
// 454.721 us; speedup vs baseline: 1.6364x; 1.0318x over previous
//
#include <hip/hip_runtime.h>

typedef _Float16 f16;
typedef f16 f16x8 __attribute__((ext_vector_type(8)));
typedef float f32x4 __attribute__((ext_vector_type(4)));
typedef unsigned short u16;

#define IN_CH  256
#define HID    256
#define OUT_CH 128
#define LN_EPS 1e-5f
#define NSLOT  32   // sig partial slots
#define NR     8    // node ranges (histogram privatization by range, LDS-sized)
#define NC     32   // edge chunks (per-chunk histogram copies -> atomic-free fill)
#define RS     6272 // max range size: ceil(50000/8)=6250, padded

// ---------------- fused pre-pass: range-chunk LDS histogram | cast | weight prep ----------------
// NO global atomics: block (r,c) histograms chunk c's src/dst within node range r in LDS,
// then writes per-chunk copies with plain coalesced stores.

__global__ __launch_bounds__(256) void k_pre0(const float* __restrict__ x, f16* __restrict__ xh, int nelem,
                                              const int* __restrict__ ei, int nE, int nN,
                                              int* __restrict__ deg_c, int* __restrict__ cnt_c,
                                              const float* __restrict__ sigw, const float* __restrict__ c1w,
                                              const float* __restrict__ c2w,
                                              f16* __restrict__ Wt1, f16* __restrict__ Wt2,
                                              int nCast) {
    __shared__ int hA[RS], hB[RS];
    int bid = blockIdx.x;
    int nT = nE + nN;
    if (bid < NR * NC) {
        int r = bid & (NR - 1), c = bid >> 3;
        int rsz = (nN + NR - 1) / NR;
        int r0 = r * rsz;
        int sz = nN - r0; if (sz > rsz) sz = rsz;
        for (int i = threadIdx.x; i < sz; i += 256) { hA[i] = 0; hB[i] = 0; }
        __syncthreads();
        int chunk = (nT + NC - 1) / NC;
        int e0 = c * chunk, e1 = e0 + chunk; if (e1 > nT) e1 = nT;
        for (int e = e0 + threadIdx.x; e < e1; e += 256) {
            int s, d;
            if (e < nE) { s = ei[e]; d = ei[nE + e]; } else { s = d = e - nE; }
            if ((unsigned)(s - r0) < (unsigned)sz) atomicAdd(&hA[s - r0], 1);
            if ((unsigned)(d - r0) < (unsigned)sz) atomicAdd(&hB[d - r0], 1);
        }
        __syncthreads();
        for (int i = threadIdx.x; i < sz; i += 256) {
            deg_c[(size_t)c * nN + r0 + i] = hA[i];
            cnt_c[(size_t)c * nN + r0 + i] = hB[i];
        }
    } else if (bid < NR * NC + nCast) {
        int i = (bid - NR * NC) * 2048 + threadIdx.x * 8;
        if (i >= nelem) return;
        float4 a = *(const float4*)(x + i);
        float4 b = *(const float4*)(x + i + 4);
        f16x8 o = { (f16)a.x, (f16)a.y, (f16)a.z, (f16)a.w,
                    (f16)b.x, (f16)b.y, (f16)b.z, (f16)b.w };
        *(f16x8*)(xh + i) = o;
    } else {
        int i = (bid - NR * NC - nCast) * 256 + threadIdx.x;
        if (i < 512 * 256) {
            int n = i >> 8, k = i & 255;
            float v = (n < 256) ? sigw[k * 256 + n] : c1w[k * 256 + (n - 256)];
            Wt1[(size_t)n * 256 + k] = (f16)v;
        } else {
            int j = i - 512 * 256;
            if (j < 128 * 256) {
                int n = j >> 8, k = j & 255;
                Wt2[(size_t)n * 256 + k] = (f16)c2w[k * 128 + n];
            }
        }
    }
}

// reduce NC chunk copies -> totals, dinv, CSR slice alloc (wave-prefix + 1 atomic/wave),
// and per-chunk base offsets (makes fill atomic-free)
__global__ __launch_bounds__(256) void k_alloc(const int* __restrict__ cnt_c,
                                               const int* __restrict__ deg_c,
                                               int* __restrict__ rowstart,
                                               int* __restrict__ chunkbase,
                                               int* __restrict__ cnt_tot,
                                               float* __restrict__ dinv,
                                               int* __restrict__ ctr, int nN) {
    int i = blockIdx.x * 256 + threadIdx.x;
    int lane = threadIdx.x & 63;
    int cc[NC];
    int cnt = 0, dg = 0;
    if (i < nN) {
        #pragma unroll
        for (int c = 0; c < NC; c++) {
            cc[c] = cnt_c[(size_t)c * nN + i];
            cnt += cc[c];
            dg += deg_c[(size_t)c * nN + i];
        }
    }
    int p = cnt;
    #pragma unroll
    for (int off = 1; off < 64; off <<= 1) {
        int v = __shfl_up(p, off, 64);
        if (lane >= off) p += v;
    }
    int tot = __shfl(p, 63, 64);
    int base = 0;
    if (lane == 0) base = atomicAdd(ctr, tot);
    base = __shfl(base, 0, 64);
    if (i < nN) {
        int nb = base + p - cnt;
        rowstart[i] = nb;
        cnt_tot[i] = cnt;
        dinv[i] = rsqrtf((float)dg);  // deg >= 1 (self loop)
        int run = nb;
        #pragma unroll
        for (int c = 0; c < NC; c++) { chunkbase[(size_t)c * nN + i] = run; run += cc[c]; }
    }
}

// fill via counting sort (LDS offsets, no global atomics) + fused xh *= dinv[row] scaling
__global__ __launch_bounds__(256) void k_fill(const int* __restrict__ ei, int nE, int nN,
                                              const int* __restrict__ chunkbase,
                                              u16* __restrict__ src_sorted,
                                              f16* __restrict__ xh, const float* __restrict__ dinv,
                                              int nScale) {
    __shared__ int off_[RS], bs[RS];
    int bid = blockIdx.x;
    int nT = nE + nN;
    if (bid < NR * NC) {
        int r = bid & (NR - 1), c = bid >> 3;
        int rsz = (nN + NR - 1) / NR;
        int r0 = r * rsz;
        int sz = nN - r0; if (sz > rsz) sz = rsz;
        for (int i = threadIdx.x; i < sz; i += 256) {
            off_[i] = 0;
            bs[i] = chunkbase[(size_t)c * nN + r0 + i];
        }
        __syncthreads();
        int chunk = (nT + NC - 1) / NC;
        int e0 = c * chunk, e1 = e0 + chunk; if (e1 > nT) e1 = nT;
        for (int e = e0 + threadIdx.x; e < e1; e += 256) {
            int s, d;
            if (e < nE) { s = ei[e]; d = ei[nE + e]; } else { s = d = e - nE; }
            int l = d - r0;
            if ((unsigned)l < (unsigned)sz) {
                int pos = bs[l] + atomicAdd(&off_[l], 1);
                src_sorted[pos] = (u16)s;
            }
        }
    } else {
        int sb = bid - NR * NC;
        if (sb >= nScale) return;
        int i = sb * 2048 + threadIdx.x * 8;
        if (i >= nN * 256) return;
        float dn = dinv[i >> 8];
        f16x8 v = *(const f16x8*)(xh + i);
        #pragma unroll
        for (int j = 0; j < 8; j++) v[j] = (f16)((float)v[j] * dn);
        *(f16x8*)(xh + i) = v;
    }
}

// ---------------- AX = dinv_d * sum(xh'[src])  (xh pre-scaled by dinv_src) ----------------
// wave per node; half-wave per edge; 16B loads; x2 unroll = 4 gathers in flight

__global__ __launch_bounds__(256) void k_aggX(const f16* __restrict__ xh,
                                              const int* __restrict__ rowstart,
                                              const int* __restrict__ counts,
                                              const u16* __restrict__ srcs,
                                              const float* __restrict__ dinv,
                                              f16* __restrict__ AX, int nN) {
    int wv = threadIdx.x >> 6;
    int lane = threadIdx.x & 63;
    int node = blockIdx.x * 4 + wv;
    if (node >= nN) return;
    int h = lane >> 5, sub = lane & 31;
    int beg = rowstart[node];
    int end = beg + counts[node];
    float acc0[8] = {}, acc1[8] = {};
    for (int e0 = beg; e0 < end; e0 += 4) {
        int ea = e0 + h, eb = e0 + 2 + h;
        bool oka = ea < end, okb = eb < end;
        int ia = oka ? ea : beg;
        int ib = okb ? eb : beg;
        int sa = srcs[ia], sb = srcs[ib];
        float na = oka ? 1.f : 0.f;
        float nb = okb ? 1.f : 0.f;
        f16x8 va = *(const f16x8*)(xh + (size_t)sa * 256 + sub * 8);
        f16x8 vb = *(const f16x8*)(xh + (size_t)sb * 256 + sub * 8);
        #pragma unroll
        for (int j = 0; j < 8; j++) {
            acc0[j] = fmaf(na, (float)va[j], acc0[j]);
            acc1[j] = fmaf(nb, (float)vb[j], acc1[j]);
        }
    }
    float dn = dinv[node];
    #pragma unroll
    for (int j = 0; j < 8; j++) {
        acc0[j] += acc1[j];
        acc0[j] += __shfl_xor(acc0[j], 32, 64);
    }
    if (lane < 32) {
        f16x8 o;
        #pragma unroll
        for (int j = 0; j < 8; j++) o[j] = (f16)(acc0[j] * dn);
        *(f16x8*)(AX + (size_t)node * 256 + sub * 8) = o;
    }
}

// ---------------- GEMM(sig): relu(AX @ sig_w + sigb) column-summed -> sig_part ----------------

__global__ __launch_bounds__(256) void k_gemm_sig(const f16* __restrict__ AX,
                                                  const f16* __restrict__ Wt,
                                                  const float* __restrict__ sigb,
                                                  float* __restrict__ sig_part, int M) {
    __shared__ float tile[32][257];
    int t = threadIdx.x;
    int w = t >> 6, lane = t & 63, quad = lane >> 4, l16 = lane & 15;
    int m0 = blockIdx.x * 32;
    int cb = w * 64;
    f32x4 acc[2][4] = {};
    for (int kk = 0; kk < 256; kk += 32) {
        int ka = kk + quad * 8;
        f16x8 a[2];
        #pragma unroll
        for (int ms = 0; ms < 2; ms++) {
            int row = m0 + ms * 16 + l16; if (row >= M) row = M - 1;
            a[ms] = *(const f16x8*)(AX + (size_t)row * 256 + ka);
        }
        #pragma unroll
        for (int ns = 0; ns < 4; ns++) {
            f16x8 b = *(const f16x8*)(Wt + (size_t)(cb + ns * 16 + l16) * 256 + ka);
            acc[0][ns] = __builtin_amdgcn_mfma_f32_16x16x32_f16(a[0], b, acc[0][ns], 0, 0, 0);
            acc[1][ns] = __builtin_amdgcn_mfma_f32_16x16x32_f16(a[1], b, acc[1][ns], 0, 0, 0);
        }
    }
    #pragma unroll
    for (int ms = 0; ms < 2; ms++)
        #pragma unroll
        for (int ns = 0; ns < 4; ns++)
            #pragma unroll
            for (int r = 0; r < 4; r++) {
                int mr = ms * 16 + quad * 4 + r;
                int c = cb + ns * 16 + l16;
                float v = fmaxf(acc[ms][ns][r] + sigb[c], 0.f);
                if (m0 + mr >= M) v = 0.f;
                tile[mr][c] = v;
            }
    __syncthreads();
    float s = 0.f;
    #pragma unroll 8
    for (int r = 0; r < 32; r++) s += tile[r][t];
    atomicAdd(&sig_part[(blockIdx.x & (NSLOT - 1)) * 256 + t], s);
}

// ---------------- FC: reduce slots -> s, then gamma/beta = tanh(s @ W.T + b) ----------------

__global__ __launch_bounds__(256) void k_fc(const float* __restrict__ sig_part,
                                            const float* __restrict__ f1w, const float* __restrict__ f1b,
                                            const float* __restrict__ f2w, const float* __restrict__ f2b,
                                            const float* __restrict__ f3w, const float* __restrict__ f3b,
                                            const float* __restrict__ f4w, const float* __restrict__ f4b,
                                            float* __restrict__ g1, float* __restrict__ b1,
                                            float* __restrict__ g2, float* __restrict__ b2) {
    __shared__ float ss[256];
    int t = threadIdx.x;
    float s = 0.f;
    for (int k = 0; k < NSLOT; k++) s += sig_part[k * 256 + t];
    ss[t] = s;
    __syncthreads();
    float a1 = 0.f, a2 = 0.f, a3 = 0.f, a4 = 0.f;
    const float* w1 = f1w + (size_t)t * 256;
    const float* w2 = f2w + (size_t)t * 256;
    const float* w3 = f3w + (size_t)(t & 127) * 256;
    const float* w4 = f4w + (size_t)(t & 127) * 256;
    for (int j = 0; j < 256; j++) {
        float sj = ss[j];
        a1 = fmaf(w1[j], sj, a1); a2 = fmaf(w2[j], sj, a2);
        a3 = fmaf(w3[j], sj, a3); a4 = fmaf(w4[j], sj, a4);
    }
    g1[t] = tanhf(a1 + f1b[t]);
    b1[t] = tanhf(a2 + f2b[t]);
    if (t < 128) {
        g2[t] = tanhf(a3 + f3b[t]);
        b2[t] = tanhf(a4 + f4b[t]);
    }
}

// ---------------- fused: conv1-GEMM + FiLM + relu + LN -> (LDS) -> conv2-GEMM -> HW' ----------------
// HW' rows pre-scaled by dinv[m] so agg2 needs no per-edge dinv gather

__global__ __launch_bounds__(256) void k_c1f(const f16* __restrict__ AX,
                                             const f16* __restrict__ Wt,   // conv1 rows (256x256)
                                             const f16* __restrict__ Wt2,  // conv2 rows (128x256)
                                             const float* __restrict__ g1,
                                             const float* __restrict__ b1,
                                             const float* __restrict__ c1b,
                                             const float* __restrict__ dinv,
                                             f16* __restrict__ HW, int M) {
    __shared__ float tile[32][257];
    __shared__ f16 ht[32][264];
    __shared__ float ps[8][33], ps2[8][33];
    __shared__ float mu_[32], rr_[32], sdinv[32];
    int t = threadIdx.x;
    int w = t >> 6, lane = t & 63, quad = lane >> 4, l16 = lane & 15;
    int m0 = blockIdx.x * 32;
    int cb = w * 64;
    f32x4 acc[2][4] = {};
    for (int kk = 0; kk < 256; kk += 32) {
        int ka = kk + quad * 8;
        f16x8 a[2];
        #pragma unroll
        for (int ms = 0; ms < 2; ms++) {
            int row = m0 + ms * 16 + l16; if (row >= M) row = M - 1;
            a[ms] = *(const f16x8*)(AX + (size_t)row * 256 + ka);
        }
        #pragma unroll
        for (int ns = 0; ns < 4; ns++) {
            f16x8 b = *(const f16x8*)(Wt + (size_t)(cb + ns * 16 + l16) * 256 + ka);
            acc[0][ns] = __builtin_amdgcn_mfma_f32_16x16x32_f16(a[0], b, acc[0][ns], 0, 0, 0);
            acc[1][ns] = __builtin_amdgcn_mfma_f32_16x16x32_f16(a[1], b, acc[1][ns], 0, 0, 0);
        }
    }
    #pragma unroll
    for (int ms = 0; ms < 2; ms++)
        #pragma unroll
        for (int ns = 0; ns < 4; ns++)
            #pragma unroll
            for (int r = 0; r < 4; r++) {
                int mr = ms * 16 + quad * 4 + r;
                int c = cb + ns * 16 + l16;
                tile[mr][c] = fmaxf(fmaf(g1[c], acc[ms][ns][r], b1[c] + c1b[c]), 0.f);
            }
    __syncthreads();
    {
        int r = t & 31, seg = t >> 5;
        float s = 0.f, s2 = 0.f;
        #pragma unroll 8
        for (int c = seg * 32; c < seg * 32 + 32; c++) {
            float xv = tile[r][c];
            s += xv; s2 = fmaf(xv, xv, s2);
        }
        ps[seg][r] = s; ps2[seg][r] = s2;
    }
    __syncthreads();
    if (t < 32) {
        float S = 0.f, S2 = 0.f;
        #pragma unroll
        for (int g = 0; g < 8; g++) { S += ps[g][t]; S2 += ps2[g][t]; }
        float mu = S * (1.f / 256.f);
        mu_[t] = mu;
        rr_[t] = rsqrtf(S2 * (1.f / 256.f) - mu * mu + LN_EPS);
        int m = m0 + t;
        sdinv[t] = (m < M) ? dinv[m] : 0.f;
    }
    __syncthreads();
    #pragma unroll 8
    for (int r = 0; r < 32; r++)
        ht[r][t] = (f16)((tile[r][t] - mu_[r]) * rr_[r]);
    __syncthreads();
    int cb2 = w * 32;
    f32x4 acc2[2][2] = {};
    for (int kk = 0; kk < 256; kk += 32) {
        int ka = kk + quad * 8;
        f16x8 a[2];
        #pragma unroll
        for (int ms = 0; ms < 2; ms++)
            a[ms] = *(const f16x8*)(&ht[ms * 16 + l16][ka]);
        #pragma unroll
        for (int ns = 0; ns < 2; ns++) {
            f16x8 b = *(const f16x8*)(Wt2 + (size_t)(cb2 + ns * 16 + l16) * 256 + ka);
            acc2[0][ns] = __builtin_amdgcn_mfma_f32_16x16x32_f16(a[0], b, acc2[0][ns], 0, 0, 0);
            acc2[1][ns] = __builtin_amdgcn_mfma_f32_16x16x32_f16(a[1], b, acc2[1][ns], 0, 0, 0);
        }
    }
    #pragma unroll
    for (int ms = 0; ms < 2; ms++)
        #pragma unroll
        for (int ns = 0; ns < 2; ns++)
            #pragma unroll
            for (int r = 0; r < 4; r++) {
                int mr = ms * 16 + quad * 4 + r;
                int m = m0 + mr;
                if (m < M) HW[(size_t)m * 128 + cb2 + ns * 16 + l16] = (f16)(acc2[ms][ns][r] * sdinv[mr]);
            }
}

// ---------------- agg2: out = LN(g2 * dinv_d * sum(HW'[src]) + b2 + c2b) ----------------
// wave per node; quarter-wave per edge; x2 unroll = 8 gathers in flight

__global__ __launch_bounds__(256) void k_agg2(const f16* __restrict__ HW,
                                              const int* __restrict__ rowstart,
                                              const int* __restrict__ counts,
                                              const u16* __restrict__ srcs,
                                              const float* __restrict__ dinv,
                                              const float* __restrict__ g2,
                                              const float* __restrict__ b2,
                                              const float* __restrict__ c2b,
                                              float* __restrict__ out, int nN) {
    int wv = threadIdx.x >> 6;
    int lane = threadIdx.x & 63;
    int node = blockIdx.x * 4 + wv;
    if (node >= nN) return;
    int q = lane >> 4, sub = lane & 15;
    int beg = rowstart[node];
    int end = beg + counts[node];
    float acc0[8] = {}, acc1[8] = {};
    for (int e0 = beg; e0 < end; e0 += 8) {
        int ea = e0 + q, eb = e0 + 4 + q;
        bool oka = ea < end, okb = eb < end;
        int ia = oka ? ea : beg;
        int ib = okb ? eb : beg;
        int sa = srcs[ia], sb = srcs[ib];
        float na = oka ? 1.f : 0.f;
        float nb = okb ? 1.f : 0.f;
        f16x8 va = *(const f16x8*)(HW + (size_t)sa * 128 + sub * 8);
        f16x8 vb = *(const f16x8*)(HW + (size_t)sb * 128 + sub * 8);
        #pragma unroll
        for (int j = 0; j < 8; j++) {
            acc0[j] = fmaf(na, (float)va[j], acc0[j]);
            acc1[j] = fmaf(nb, (float)vb[j], acc1[j]);
        }
    }
    float dn = dinv[node];
    #pragma unroll
    for (int j = 0; j < 8; j++) {
        acc0[j] += acc1[j];
        acc0[j] += __shfl_xor(acc0[j], 16, 64);
        acc0[j] += __shfl_xor(acc0[j], 32, 64);
    }
    int ch = sub * 8;
    float vfin[8];
    float s = 0.f, s2 = 0.f;
    #pragma unroll
    for (int j = 0; j < 8; j++) {
        float v = fmaf(g2[ch + j], acc0[j] * dn, b2[ch + j] + c2b[ch + j]);
        vfin[j] = v;
        s += v; s2 = fmaf(v, v, s2);
    }
    #pragma unroll
    for (int off = 1; off < 16; off <<= 1) {
        s += __shfl_xor(s, off, 64);
        s2 += __shfl_xor(s2, off, 64);
    }
    float mu = s * (1.f / 128.f);
    float rr = rsqrtf(s2 * (1.f / 128.f) - mu * mu + LN_EPS);
    if (q == 0) {
        float4 o0 = { (vfin[0] - mu) * rr, (vfin[1] - mu) * rr,
                      (vfin[2] - mu) * rr, (vfin[3] - mu) * rr };
        float4 o1 = { (vfin[4] - mu) * rr, (vfin[5] - mu) * rr,
                      (vfin[6] - mu) * rr, (vfin[7] - mu) * rr };
        float* dst = out + (size_t)node * 128 + ch;
        *(float4*)dst = o0;
        *(float4*)(dst + 4) = o1;
    }
}

// ---------------- host launch ----------------

extern "C" void kernel_launch(void* const* d_in, const int* in_sizes, int n_in,
                              void* d_out, int out_size, void* d_ws, size_t ws_size,
                              hipStream_t stream) {
    const float* x    = (const float*)d_in[0];
    const int*   ei   = (const int*)d_in[1];
    const float* c1w  = (const float*)d_in[2];
    const float* c1b  = (const float*)d_in[3];
    const float* c2w  = (const float*)d_in[4];
    const float* c2b  = (const float*)d_in[5];
    const float* sigw = (const float*)d_in[6];
    const float* sigb = (const float*)d_in[7];
    const float* f1w  = (const float*)d_in[8];
    const float* f1b  = (const float*)d_in[9];
    const float* f2w  = (const float*)d_in[10];
    const float* f2b  = (const float*)d_in[11];
    const float* f3w  = (const float*)d_in[12];
    const float* f3b  = (const float*)d_in[13];
    const float* f4w  = (const float*)d_in[14];
    const float* f4b  = (const float*)d_in[15];
    float* out = (float*)d_out;

    int nN = in_sizes[0] / IN_CH;      // 50000
    int nE = in_sizes[1] / 2;          // 800000
    int nT = nE + nN;                  // 850000

    char* base = (char*)d_ws;
    size_t off = 0;
    auto alloc = [&](size_t bytes) { size_t o = off; off += (bytes + 255) & ~(size_t)255; return o; };

    size_t o_spart  = alloc((size_t)NSLOT * 256 * 4);
    size_t o_ctr    = alloc(256);
    size_t zero_bytes = off;                   // zero sig_part/ctr only
    size_t o_degc   = alloc((size_t)NC * nN * 4);
    size_t o_cntc   = alloc((size_t)NC * nN * 4);
    size_t o_cbase  = alloc((size_t)NC * nN * 4);
    size_t o_g1     = alloc(256 * 4);
    size_t o_b1     = alloc(256 * 4);
    size_t o_g2     = alloc(128 * 4);
    size_t o_b2     = alloc(128 * 4);
    size_t o_rowst  = alloc((size_t)nN * 4);
    size_t o_cntt   = alloc((size_t)nN * 4);
    size_t o_dinv   = alloc((size_t)nN * 4);
    size_t o_src    = alloc((size_t)nT * 2);
    size_t o_wt1    = alloc(512 * 256 * 2);
    size_t o_wt2    = alloc(128 * 256 * 2);
    size_t o_xh     = alloc((size_t)nN * 256 * 2);
    size_t o_AX     = alloc((size_t)nN * 256 * 2);
    size_t o_HW     = alloc((size_t)nN * 128 * 2);

    float* spart  = (float*)(base + o_spart);
    int*   ctr    = (int*)(base + o_ctr);
    int*   degc   = (int*)(base + o_degc);
    int*   cntc   = (int*)(base + o_cntc);
    int*   cbase  = (int*)(base + o_cbase);
    float* g1     = (float*)(base + o_g1);
    float* b1     = (float*)(base + o_b1);
    float* g2     = (float*)(base + o_g2);
    float* b2     = (float*)(base + o_b2);
    int*   rowst  = (int*)(base + o_rowst);
    int*   cntt   = (int*)(base + o_cntt);
    float* dinv   = (float*)(base + o_dinv);
    u16*   srcs   = (u16*)(base + o_src);
    f16*   Wt1    = (f16*)(base + o_wt1);
    f16*   Wt2    = (f16*)(base + o_wt2);
    f16*   xh     = (f16*)(base + o_xh);
    f16*   AX     = (f16*)(base + o_AX);
    f16*   HW     = (f16*)(base + o_HW);

    hipMemsetAsync(base, 0, zero_bytes, stream);

    int nCast = (nN * IN_CH + 2047) / 2048;            // 6250
    int nPrep = (512 * 256 + 128 * 256) / 256;         // 640
    k_pre0<<<NR * NC + nCast + nPrep, 256, 0, stream>>>(x, xh, nN * IN_CH, ei, nE, nN,
                                                        degc, cntc, sigw, c1w, c2w, Wt1, Wt2, nCast);
    k_alloc<<<(nN + 255) / 256, 256, 0, stream>>>(cntc, degc, rowst, cbase, cntt, dinv, ctr, nN);

    int nScale = (nN * IN_CH + 2047) / 2048;
    k_fill<<<NR * NC + nScale, 256, 0, stream>>>(ei, nE, nN, cbase, srcs, xh, dinv, nScale);

    int nb4 = (nN + 3) / 4;
    int mg = (nN + 31) / 32;
    k_aggX<<<nb4, 256, 0, stream>>>(xh, rowst, cntt, srcs, dinv, AX, nN);
    k_gemm_sig<<<mg, 256, 0, stream>>>(AX, Wt1, sigb, spart, nN);
    k_fc<<<1, 256, 0, stream>>>(spart, f1w, f1b, f2w, f2b, f3w, f3b, f4w, f4b, g1, b1, g2, b2);
    k_c1f<<<mg, 256, 0, stream>>>(AX, Wt1 + 256 * 256, Wt2, g1, b1, c1b, dinv, HW, nN);
    k_agg2<<<nb4, 256, 0, stream>>>(HW, rowst, cntt, srcs, dinv, g2, b2, c2b, out, nN);
}